// Round 4
// baseline (4057.773 us; speedup 1.0000x reference)
//
#include <hip/hip_runtime.h>
#include <math.h>

#define D_MODEL 256
#define NHEAD   8
#define D_K     32
#define LSEQ    2048
#define BATCH   2
#define ROWS    (BATCH * LSEQ)   // 4096
#define D_FF    1024
#define UTOP    38

// ---------------------------------------------------------------------------
// Embedding + positional encoding
// ---------------------------------------------------------------------------
__global__ __launch_bounds__(256) void k_embed(const float* __restrict__ x,
                                               const float* __restrict__ w,
                                               const float* __restrict__ b,
                                               float* __restrict__ h) {
    int row = blockIdx.x;           // b*L + l
    int l   = row & (LSEQ - 1);
    int d   = threadIdx.x;
    __shared__ float xs[32];
    if (d < 32) xs[d] = x[row * 32 + d];
    __syncthreads();
    float acc = 0.f;
#pragma unroll
    for (int i = 0; i < 32; ++i) acc += xs[i] * w[i * D_MODEL + d];
    acc = (acc + b[d]) * 16.0f;     // sqrt(256)
    int m = d >> 1;
    float div = expf(-(float)(2 * m) * (9.210340371976184f / 256.0f)); // ln(1e4)/256
    float ang = (float)l * div;
    float pe = (d & 1) ? cosf(ang) : sinf(ang);
    h[row * D_MODEL + d] = acc + pe;
}

// ---------------------------------------------------------------------------
// Generic fp32 tiled GEMM: C = A[M,K] @ W[K,N] + bias
// MODE 0: plain   MODE 1: relu   MODE 2: scatter to q/k/v layout [B,H,L,32]
// ---------------------------------------------------------------------------
template <int MODE>
__global__ __launch_bounds__(256) void k_gemm(const float* __restrict__ A,
                                              const float* __restrict__ W,
                                              const float* __restrict__ bias,
                                              float* __restrict__ C,
                                              int M, int N, int K) {
    __shared__ float As[16][68];
    __shared__ float Ws[16][68];
    const int t  = threadIdx.x;
    const int tx = t & 15, ty = t >> 4;
    const int m0 = blockIdx.x * 64, n0 = blockIdx.y * 64;
    float acc[4][4] = {};
    for (int k0 = 0; k0 < K; k0 += 16) {
        {
            int mr = t >> 2, kc = (t & 3) * 4;
            float4 av = *(const float4*)&A[(size_t)(m0 + mr) * K + k0 + kc];
            As[kc + 0][mr] = av.x; As[kc + 1][mr] = av.y;
            As[kc + 2][mr] = av.z; As[kc + 3][mr] = av.w;
            int kr = t >> 4, nc = (t & 15) * 4;
            *(float4*)&Ws[kr][nc] = *(const float4*)&W[(size_t)(k0 + kr) * N + n0 + nc];
        }
        __syncthreads();
#pragma unroll
        for (int k = 0; k < 16; ++k) {
            float4 a4 = *(const float4*)&As[k][ty * 4];
            float4 w4 = *(const float4*)&Ws[k][tx * 4];
            float av[4] = {a4.x, a4.y, a4.z, a4.w};
            float wv[4] = {w4.x, w4.y, w4.z, w4.w};
#pragma unroll
            for (int i = 0; i < 4; ++i)
#pragma unroll
                for (int j = 0; j < 4; ++j) acc[i][j] += av[i] * wv[j];
        }
        __syncthreads();
    }
#pragma unroll
    for (int i = 0; i < 4; ++i) {
        int row = m0 + ty * 4 + i;
#pragma unroll
        for (int j = 0; j < 4; ++j) {
            int col = n0 + tx * 4 + j;
            float v = acc[i][j] + bias[col];
            if (MODE == 1) v = fmaxf(v, 0.f);
            if (MODE == 2) {
                int bb = row >> 11, ll = row & (LSEQ - 1);
                int hh = col >> 5, dd = col & 31;
                C[(((size_t)(bb * NHEAD + hh) * LSEQ) + ll) * D_K + dd] = v;
            } else {
                C[(size_t)row * N + col] = v;
            }
        }
    }
}

// ---------------------------------------------------------------------------
// Fused ProbSparse attention, v3.
// Block = 4 waves (256 thr); each wave owns 2 query rows of one (b,h).
// d-split: lanes 0..31 hold q[0:16], lanes 32..63 hold q[16:32]  -> q = 32 VGPR.
// K staged via global_load_lds into a read-order-linear LDS layout:
//   granule g = r*64 + lane  <->  key 2*(lane&31) + (r>>2), half lane>>5,
//   chunk r&3.  Reads are ds_read_b128 at lane*16 + r*1024: conflict-free.
// Exact top-38 via wave-private 4x8-bit radix select.
// ---------------------------------------------------------------------------
__device__ __forceinline__ unsigned int sortkey(float f) {
    unsigned int u = __float_as_uint(f);
    return (u & 0x80000000u) ? ~u : (u | 0x80000000u);
}
__device__ __forceinline__ float key2f(unsigned int u) {
    unsigned int b = (u & 0x80000000u) ? (u ^ 0x80000000u) : ~u;
    return __uint_as_float(b);
}
__device__ __forceinline__ void gload_lds16(const float* src, float* ldsDst) {
    __builtin_amdgcn_global_load_lds(
        (const __attribute__((address_space(1))) unsigned int*)src,
        (__attribute__((address_space(3))) unsigned int*)ldsDst,
        16, 0, 0);
}

__global__ __launch_bounds__(256, 3) void k_attn(const float* __restrict__ Q,
                                                 const float* __restrict__ Kt,
                                                 const float* __restrict__ Vt,
                                                 float* __restrict__ ctxb) {
    __shared__ float Kl[2][2048];        // 2 x 8 KB
    __shared__ int   hist[4][256];       // 4 KB
    __shared__ float lv[4][96];
    __shared__ int   li[4][96];
    __shared__ int   lcnt[4];

    const int tid   = threadIdx.x;
    const int lane  = tid & 63;
    const int wid   = tid >> 6;
    const int bh    = blockIdx.x >> 8;    // 16 bh x 256 chunks
    const int chunk = blockIdx.x & 255;
    const int row0  = chunk * 8 + wid * 2;
    const int b     = bh >> 3, hh = bh & 7;
    const int h     = lane >> 5;          // d-half owned by this lane
    const int p     = lane & 31;

    const float* Kb = Kt + (size_t)bh * LSEQ * D_K;
    const float* Vb = Vt + (size_t)bh * LSEQ * D_K;
    const float* qp = Q + ((size_t)bh * LSEQ + row0) * D_K;

    const float scale = 0.17677669529663687f; // 1/sqrt(32)
    float qa[16], qc[16];
#pragma unroll
    for (int i = 0; i < 16; ++i) {
        qa[i] = qp[h * 16 + i] * scale;
        qc[i] = qp[32 + h * 16 + i] * scale;
    }

    unsigned int k0[32], k1[32];

    // stage tile t into Kl[buf]: 8 granule-rows, 2 per wave
    auto stage = [&](int t, int buf) {
#pragma unroll
        for (int i = 0; i < 2; ++i) {
            int r   = wid * 2 + i;            // 0..7
            int kk  = r >> 2, c = r & 3;
            int key = 2 * p + kk;
            const float* src = Kb + ((size_t)(t * 64 + key)) * 32 + h * 16 + c * 4;
            gload_lds16(src, &Kl[buf][r * 256]);   // HW adds lane*16B
        }
    };

    stage(0, 0);
    asm volatile("s_waitcnt vmcnt(0)" ::: "memory");
    __syncthreads();

    int buf = 0;
#pragma unroll
    for (int t = 0; t < 32; ++t) {
        if (t < 31) stage(t + 1, buf ^ 1);
        float pA0 = 0.f, pA1 = 0.f, pB0 = 0.f, pB1 = 0.f;
#pragma unroll
        for (int c = 0; c < 4; ++c) {
            float4 kva = *(const float4*)&Kl[buf][c * 256 + lane * 4];         // key 2p
            float4 kvb = *(const float4*)&Kl[buf][(4 + c) * 256 + lane * 4];   // key 2p+1
            pA0 += qa[c*4+0]*kva.x + qa[c*4+1]*kva.y + qa[c*4+2]*kva.z + qa[c*4+3]*kva.w;
            pA1 += qc[c*4+0]*kva.x + qc[c*4+1]*kva.y + qc[c*4+2]*kva.z + qc[c*4+3]*kva.w;
            pB0 += qa[c*4+0]*kvb.x + qa[c*4+1]*kvb.y + qa[c*4+2]*kvb.z + qa[c*4+3]*kvb.w;
            pB1 += qc[c*4+0]*kvb.x + qc[c*4+1]*kvb.y + qc[c*4+2]*kvb.z + qc[c*4+3]*kvb.w;
        }
        float fA0 = pA0 + __shfl_xor(pA0, 32);
        float fB0 = pB0 + __shfl_xor(pB0, 32);
        float fA1 = pA1 + __shfl_xor(pA1, 32);
        float fB1 = pB1 + __shfl_xor(pB1, 32);
        k0[t] = sortkey(h ? fB0 : fA0);     // lane keeps key 2p + h
        k1[t] = sortkey(h ? fB1 : fA1);
        asm volatile("s_waitcnt vmcnt(0)" ::: "memory");
        __syncthreads();
        buf ^= 1;
    }

    // per-wave select + softmax + PV (waves independent from here on)
    auto do_row = [&](const unsigned int (&kr)[32], int rr) {
        unsigned int mk = 0;
#pragma unroll
        for (int j = 0; j < 32; ++j) mk = max(mk, kr[j]);
#pragma unroll
        for (int off = 32; off >= 1; off >>= 1) {
            unsigned int o = (unsigned int)__shfl_xor((int)mk, off);
            if (o > mk) mk = o;
        }
        const float rowmax = key2f(mk);

        unsigned int prefix = 0;
        int need = UTOP;
#pragma unroll
        for (int pass = 0; pass < 4; ++pass) {
            const int sh = 24 - pass * 8;
            *(int4*)&hist[wid][lane * 4] = make_int4(0, 0, 0, 0);
#pragma unroll
            for (int j = 0; j < 32; ++j) {
                unsigned int key = kr[j];
                bool m = (pass == 0) || ((key >> (sh + 8)) == (prefix >> (sh + 8)));
                if (m) atomicAdd(&hist[wid][(key >> sh) & 255], 1);
            }
            int4 hb = *(const int4*)&hist[wid][lane * 4];
            int c0 = hb.x, c1 = hb.y, c2 = hb.z, c3 = hb.w;
            int csum = c0 + c1 + c2 + c3;
            int suf = csum;
#pragma unroll
            for (int off = 1; off < 64; off <<= 1) {
                int o = __shfl_down(suf, off);
                if (lane + off < 64) suf += o;
            }
            int above = suf - csum;   // keys in strictly-higher bins
            bool found = (above < need) && (above + csum >= need);
            unsigned int cp = 0; int cn = 0;
            if (found) {
                int cum = above, d, na;
                if (cum + c3 >= need)      { d = 3; na = cum; }
                else { cum += c3;
                if (cum + c2 >= need)      { d = 2; na = cum; }
                else { cum += c2;
                if (cum + c1 >= need)      { d = 1; na = cum; }
                else { cum += c1;            d = 0; na = cum; } } }
                cp = prefix | ((unsigned int)(lane * 4 + d) << sh);
                cn = need - na;
            }
            unsigned long long bal = __ballot(found);
            int wl = (int)(__ffsll((unsigned long long)bal) - 1);
            prefix = (unsigned int)__shfl((int)cp, wl);
            need   = __shfl(cn, wl);
        }
        const unsigned int thrkey = prefix;   // exact 38th-largest key

        if (lane == 0) lcnt[wid] = 0;
#pragma unroll
        for (int j = 0; j < 32; ++j) {
            if (kr[j] >= thrkey) {
                int slot = atomicAdd(&lcnt[wid], 1);
                if (slot < 96) {
                    lv[wid][slot] = key2f(kr[j]);
                    li[wid][slot] = j * 64 + 2 * p + h;
                }
            }
        }
        int cnt = lcnt[wid]; if (cnt > 96) cnt = 96;

        float psum = 0.f;
        for (int i = lane; i < cnt; i += 64) psum += expf(lv[wid][i] - rowmax);
#pragma unroll
        for (int off = 32; off >= 1; off >>= 1) psum += __shfl_xor(psum, off);
        float inv = 1.0f / psum;

        int d = lane & 31, half = lane >> 5;
        float acc = 0.f;
        for (int i = half; i < cnt; i += 2)
            acc += expf(lv[wid][i] - rowmax) * Vb[(size_t)li[wid][i] * D_K + d];
        acc += __shfl_xor(acc, 32);
        if (lane < 32)
            ctxb[((size_t)(b * LSEQ) + (row0 + rr)) * D_MODEL + hh * D_K + d] = acc * inv;
    };

    do_row(k0, 0);
    do_row(k1, 1);
}

// ---------------------------------------------------------------------------
// Residual add + LayerNorm over 256, in place into h. One wave per row.
// ---------------------------------------------------------------------------
__global__ __launch_bounds__(64) void k_addln(float* __restrict__ h,
                                              const float* __restrict__ a,
                                              const float* __restrict__ g,
                                              const float* __restrict__ bb) {
    int row = blockIdx.x, lane = threadIdx.x;
    float4 hv = *(const float4*)&h[(size_t)row * D_MODEL + lane * 4];
    float4 av = *(const float4*)&a[(size_t)row * D_MODEL + lane * 4];
    float x0 = hv.x + av.x, x1 = hv.y + av.y, x2 = hv.z + av.z, x3 = hv.w + av.w;
    float s = x0 + x1 + x2 + x3;
#pragma unroll
    for (int off = 32; off >= 1; off >>= 1) s += __shfl_xor(s, off);
    float mean = s * (1.0f / 256.0f);
    float d0 = x0 - mean, d1 = x1 - mean, d2 = x2 - mean, d3 = x3 - mean;
    float vs = d0 * d0 + d1 * d1 + d2 * d2 + d3 * d3;
#pragma unroll
    for (int off = 32; off >= 1; off >>= 1) vs += __shfl_xor(vs, off);
    float inv = rsqrtf(vs * (1.0f / 256.0f) + 1e-5f);
    float4 gv = *(const float4*)&g[lane * 4];
    float4 bv = *(const float4*)&bb[lane * 4];
    float4 o;
    o.x = d0 * inv * gv.x + bv.x;
    o.y = d1 * inv * gv.y + bv.y;
    o.z = d2 * inv * gv.z + bv.z;
    o.w = d3 * inv * gv.w + bv.w;
    *(float4*)&h[(size_t)row * D_MODEL + lane * 4] = o;
}

// ---------------------------------------------------------------------------
// Decoder head
// ---------------------------------------------------------------------------
__global__ __launch_bounds__(64) void k_dec(const float* __restrict__ h,
                                            const float* __restrict__ w,
                                            const float* __restrict__ b,
                                            float* __restrict__ out) {
    int row = blockIdx.x, lane = threadIdx.x;
    int c = lane & 7, part = lane >> 3;   // 8 parts x 32 dims
    float acc = 0.f;
    int d0 = part * 32;
#pragma unroll
    for (int dd = 0; dd < 32; ++dd) acc += h[(size_t)row * D_MODEL + d0 + dd] * w[(d0 + dd) * 8 + c];
    acc += __shfl_xor(acc, 8);
    acc += __shfl_xor(acc, 16);
    acc += __shfl_xor(acc, 32);
    if (lane < 8) out[(size_t)row * 8 + c] = acc + b[c];
}

// ---------------------------------------------------------------------------
extern "C" void kernel_launch(void* const* d_in, const int* in_sizes, int n_in,
                              void* d_out, int out_size, void* d_ws, size_t ws_size,
                              hipStream_t stream) {
    const float* x     = (const float*)d_in[0];
    const float* emb_w = (const float*)d_in[1];
    const float* emb_b = (const float*)d_in[2];
    const float* wq    = (const float*)d_in[3];
    const float* bq    = (const float*)d_in[4];
    const float* wk    = (const float*)d_in[5];
    const float* bk    = (const float*)d_in[6];
    const float* wv    = (const float*)d_in[7];
    const float* bv    = (const float*)d_in[8];
    const float* wo    = (const float*)d_in[9];
    const float* bo    = (const float*)d_in[10];
    const float* ln1_g = (const float*)d_in[11];
    const float* ln1_b = (const float*)d_in[12];
    const float* ln2_g = (const float*)d_in[13];
    const float* ln2_b = (const float*)d_in[14];
    const float* ff1_w = (const float*)d_in[15];
    const float* ff1_b = (const float*)d_in[16];
    const float* ff2_w = (const float*)d_in[17];
    const float* ff2_b = (const float*)d_in[18];
    const float* dec_w = (const float*)d_in[19];
    const float* dec_b = (const float*)d_in[20];

    float* ws   = (float*)d_ws;
    float* h    = ws;                      // 4096*256   = 1M floats
    float* qb   = h    + (1 << 20);
    float* kb   = qb   + (1 << 20);
    float* vb   = kb   + (1 << 20);
    float* ctxb = vb   + (1 << 20);
    float* tmp  = ctxb + (1 << 20);
    float* ffb  = tmp  + (1 << 20);        // 4096*1024 = 4M

    k_embed<<<ROWS, 256, 0, stream>>>(x, emb_w, emb_b, h);

    for (int l = 0; l < 2; ++l) {
        const float* wql = wq + (size_t)l * 65536;  const float* bql = bq + l * 256;
        const float* wkl = wk + (size_t)l * 65536;  const float* bkl = bk + l * 256;
        const float* wvl = wv + (size_t)l * 65536;  const float* bvl = bv + l * 256;
        const float* wol = wo + (size_t)l * 65536;  const float* bol = bo + l * 256;

        dim3 g4(64, 4);
        k_gemm<2><<<g4, 256, 0, stream>>>(h, wql, bql, qb, ROWS, 256, 256);
        k_gemm<2><<<g4, 256, 0, stream>>>(h, wkl, bkl, kb, ROWS, 256, 256);
        k_gemm<2><<<g4, 256, 0, stream>>>(h, wvl, bvl, vb, ROWS, 256, 256);

        k_attn<<<NHEAD * BATCH * 256, 256, 0, stream>>>(qb, kb, vb, ctxb);

        k_gemm<0><<<g4, 256, 0, stream>>>(ctxb, wol, bol, tmp, ROWS, 256, 256);
        k_addln<<<ROWS, 64, 0, stream>>>(h, tmp, ln1_g + l * 256, ln1_b + l * 256);

        dim3 g16(64, 16);
        k_gemm<1><<<g16, 256, 0, stream>>>(h, ff1_w + (size_t)l * 262144, ff1_b + l * 1024,
                                           ffb, ROWS, D_FF, 256);
        k_gemm<0><<<g4, 256, 0, stream>>>(ffb, ff2_w + (size_t)l * 262144, ff2_b + l * 256,
                                          tmp, ROWS, 256, D_FF);
        k_addln<<<ROWS, 64, 0, stream>>>(h, tmp, ln2_g + l * 256, ln2_b + l * 256);
    }

    k_dec<<<ROWS, 64, 0, stream>>>(h, dec_w, dec_b, (float*)d_out);
}

// Round 5
// 2537.092 us; speedup vs baseline: 1.5994x; 1.5994x over previous
//
#include <hip/hip_runtime.h>
#include <math.h>

#define D_MODEL 256
#define NHEAD   8
#define D_K     32
#define LSEQ    2048
#define BATCH   2
#define ROWS    (BATCH * LSEQ)   // 4096
#define D_FF    1024
#define UTOP    38

// ---------------------------------------------------------------------------
// Embedding + positional encoding
// ---------------------------------------------------------------------------
__global__ __launch_bounds__(256) void k_embed(const float* __restrict__ x,
                                               const float* __restrict__ w,
                                               const float* __restrict__ b,
                                               float* __restrict__ h) {
    int row = blockIdx.x;           // b*L + l
    int l   = row & (LSEQ - 1);
    int d   = threadIdx.x;
    __shared__ float xs[32];
    if (d < 32) xs[d] = x[row * 32 + d];
    __syncthreads();
    float acc = 0.f;
#pragma unroll
    for (int i = 0; i < 32; ++i) acc += xs[i] * w[i * D_MODEL + d];
    acc = (acc + b[d]) * 16.0f;     // sqrt(256)
    int m = d >> 1;
    float div = expf(-(float)(2 * m) * (9.210340371976184f / 256.0f)); // ln(1e4)/256
    float ang = (float)l * div;
    float pe = (d & 1) ? cosf(ang) : sinf(ang);
    h[row * D_MODEL + d] = acc + pe;
}

// ---------------------------------------------------------------------------
// Generic fp32 tiled GEMM: C = A[M,K] @ W[K,N] + bias
// MODE 0: plain   MODE 1: relu   MODE 2: scatter to q/k/v layout [B,H,L,32]
// ---------------------------------------------------------------------------
template <int MODE>
__global__ __launch_bounds__(256) void k_gemm(const float* __restrict__ A,
                                              const float* __restrict__ W,
                                              const float* __restrict__ bias,
                                              float* __restrict__ C,
                                              int M, int N, int K) {
    __shared__ float As[16][68];
    __shared__ float Ws[16][68];
    const int t  = threadIdx.x;
    const int tx = t & 15, ty = t >> 4;
    const int m0 = blockIdx.x * 64, n0 = blockIdx.y * 64;
    float acc[4][4] = {};
    for (int k0 = 0; k0 < K; k0 += 16) {
        {
            int mr = t >> 2, kc = (t & 3) * 4;
            float4 av = *(const float4*)&A[(size_t)(m0 + mr) * K + k0 + kc];
            As[kc + 0][mr] = av.x; As[kc + 1][mr] = av.y;
            As[kc + 2][mr] = av.z; As[kc + 3][mr] = av.w;
            int kr = t >> 4, nc = (t & 15) * 4;
            *(float4*)&Ws[kr][nc] = *(const float4*)&W[(size_t)(k0 + kr) * N + n0 + nc];
        }
        __syncthreads();
#pragma unroll
        for (int k = 0; k < 16; ++k) {
            float4 a4 = *(const float4*)&As[k][ty * 4];
            float4 w4 = *(const float4*)&Ws[k][tx * 4];
            float av[4] = {a4.x, a4.y, a4.z, a4.w};
            float wv[4] = {w4.x, w4.y, w4.z, w4.w};
#pragma unroll
            for (int i = 0; i < 4; ++i)
#pragma unroll
                for (int j = 0; j < 4; ++j) acc[i][j] += av[i] * wv[j];
        }
        __syncthreads();
    }
#pragma unroll
    for (int i = 0; i < 4; ++i) {
        int row = m0 + ty * 4 + i;
#pragma unroll
        for (int j = 0; j < 4; ++j) {
            int col = n0 + tx * 4 + j;
            float v = acc[i][j] + bias[col];
            if (MODE == 1) v = fmaxf(v, 0.f);
            if (MODE == 2) {
                int bb = row >> 11, ll = row & (LSEQ - 1);
                int hh = col >> 5, dd = col & 31;
                C[(((size_t)(bb * NHEAD + hh) * LSEQ) + ll) * D_K + dd] = v;
            } else {
                C[(size_t)row * N + col] = v;
            }
        }
    }
}

// ---------------------------------------------------------------------------
// Fused ProbSparse attention, v4.
// Same algorithm as v3, but the per-row select/softmax/PV is stamped by a
// MACRO on the named register arrays k0/k1 -- no lambda, no array-by-
// reference, no address-taken locals => no scratch spill (rule #20).
// ---------------------------------------------------------------------------
__device__ __forceinline__ unsigned int sortkey(float f) {
    unsigned int u = __float_as_uint(f);
    return (u & 0x80000000u) ? ~u : (u | 0x80000000u);
}
__device__ __forceinline__ float key2f(unsigned int u) {
    unsigned int b = (u & 0x80000000u) ? (u ^ 0x80000000u) : ~u;
    return __uint_as_float(b);
}
__device__ __forceinline__ void gload_lds16(const float* src, float* ldsDst) {
    __builtin_amdgcn_global_load_lds(
        (const __attribute__((address_space(1))) unsigned int*)src,
        (__attribute__((address_space(3))) unsigned int*)ldsDst,
        16, 0, 0);
}

// select + softmax + PV for one row; KR is a named register array (k0/k1),
// every access has a compile-time index.
#define SELECT_ROW(KR, RR)                                                      \
{                                                                               \
    unsigned int mk = 0;                                                        \
    _Pragma("unroll") for (int j = 0; j < 32; ++j) mk = max(mk, KR[j]);         \
    _Pragma("unroll") for (int off = 32; off >= 1; off >>= 1) {                 \
        unsigned int o = (unsigned int)__shfl_xor((int)mk, off);                \
        if (o > mk) mk = o;                                                     \
    }                                                                           \
    const float rowmax = key2f(mk);                                             \
    unsigned int prefix = 0;                                                    \
    int need = UTOP;                                                            \
    _Pragma("unroll") for (int pass = 0; pass < 4; ++pass) {                    \
        const int sh = 24 - pass * 8;                                           \
        *(int4*)&hist[wid][lane * 4] = make_int4(0, 0, 0, 0);                   \
        _Pragma("unroll") for (int j = 0; j < 32; ++j) {                        \
            unsigned int key = KR[j];                                           \
            bool msk = (pass == 0) || ((key >> (sh + 8)) == (prefix >> (sh + 8)));\
            if (msk) atomicAdd(&hist[wid][(key >> sh) & 255], 1);               \
        }                                                                       \
        int4 hb = *(const int4*)&hist[wid][lane * 4];                           \
        int csum = hb.x + hb.y + hb.z + hb.w;                                   \
        int suf = csum;                                                         \
        _Pragma("unroll") for (int off = 1; off < 64; off <<= 1) {              \
            int o = __shfl_down(suf, off);                                      \
            if (lane + off < 64) suf += o;                                      \
        }                                                                       \
        int above = suf - csum;                                                 \
        bool found = (above < need) && (above + csum >= need);                  \
        unsigned int cp = 0; int cn = 0;                                        \
        if (found) {                                                            \
            int cum = above, dd, na;                                            \
            if (cum + hb.w >= need)      { dd = 3; na = cum; }                  \
            else { cum += hb.w;                                                 \
            if (cum + hb.z >= need)      { dd = 2; na = cum; }                  \
            else { cum += hb.z;                                                 \
            if (cum + hb.y >= need)      { dd = 1; na = cum; }                  \
            else { cum += hb.y;            dd = 0; na = cum; } } }              \
            cp = prefix | ((unsigned int)(lane * 4 + dd) << sh);                \
            cn = need - na;                                                     \
        }                                                                       \
        unsigned long long bal = __ballot(found);                               \
        int wl = (int)(__ffsll(bal) - 1);                                       \
        prefix = (unsigned int)__shfl((int)cp, wl);                             \
        need   = __shfl(cn, wl);                                                \
    }                                                                           \
    const unsigned int thrkey = prefix;                                         \
    if (lane == 0) lcnt[wid] = 0;                                               \
    _Pragma("unroll") for (int j = 0; j < 32; ++j) {                            \
        if (KR[j] >= thrkey) {                                                  \
            int slot = atomicAdd(&lcnt[wid], 1);                                \
            if (slot < 96) {                                                    \
                lv[wid][slot] = key2f(KR[j]);                                   \
                li[wid][slot] = j * 64 + 2 * p + h;                             \
            }                                                                   \
        }                                                                       \
    }                                                                           \
    int cnt = lcnt[wid]; if (cnt > 96) cnt = 96;                                \
    float psum = 0.f;                                                           \
    for (int i = lane; i < cnt; i += 64) psum += expf(lv[wid][i] - rowmax);     \
    _Pragma("unroll") for (int off = 32; off >= 1; off >>= 1)                   \
        psum += __shfl_xor(psum, off);                                          \
    float inv = 1.0f / psum;                                                    \
    int dcol = lane & 31, halfsel = lane >> 5;                                  \
    float acc = 0.f;                                                            \
    for (int i = halfsel; i < cnt; i += 2)                                      \
        acc += expf(lv[wid][i] - rowmax) * Vb[(size_t)li[wid][i] * D_K + dcol]; \
    acc += __shfl_xor(acc, 32);                                                 \
    if (lane < 32)                                                              \
        ctxb[((size_t)(b * LSEQ) + (row0 + RR)) * D_MODEL + hh * D_K + dcol] = acc * inv; \
}

__global__ __launch_bounds__(256, 2) void k_attn(const float* __restrict__ Q,
                                                 const float* __restrict__ Kt,
                                                 const float* __restrict__ Vt,
                                                 float* __restrict__ ctxb) {
    __shared__ float Kl[2][2048];        // 2 x 8 KB
    __shared__ int   hist[4][256];       // 4 KB
    __shared__ float lv[4][96];
    __shared__ int   li[4][96];
    __shared__ int   lcnt[4];

    const int tid   = threadIdx.x;
    const int lane  = tid & 63;
    const int wid   = tid >> 6;
    const int bh    = blockIdx.x >> 8;    // 16 bh x 256 chunks
    const int chunk = blockIdx.x & 255;
    const int row0  = chunk * 8 + wid * 2;
    const int b     = bh >> 3, hh = bh & 7;
    const int h     = lane >> 5;          // d-half owned by this lane
    const int p     = lane & 31;

    const float* Kb = Kt + (size_t)bh * LSEQ * D_K;
    const float* Vb = Vt + (size_t)bh * LSEQ * D_K;
    const float* qp = Q + ((size_t)bh * LSEQ + row0) * D_K;

    const float scale = 0.17677669529663687f; // 1/sqrt(32)
    float qa[16], qc[16];
#pragma unroll
    for (int i = 0; i < 16; ++i) {
        qa[i] = qp[h * 16 + i] * scale;
        qc[i] = qp[32 + h * 16 + i] * scale;
    }

    unsigned int k0[32], k1[32];

    // prologue: stage tile 0
#pragma unroll
    for (int i = 0; i < 2; ++i) {
        int r  = wid * 2 + i;             // 0..7
        int kk = r >> 2, cc = r & 3;
        const float* src = Kb + ((size_t)(2 * p + kk)) * 32 + h * 16 + cc * 4;
        gload_lds16(src, &Kl[0][r * 256]);
    }
    asm volatile("s_waitcnt vmcnt(0)" ::: "memory");
    __syncthreads();

    int buf = 0;
#pragma unroll
    for (int t = 0; t < 32; ++t) {
        if (t < 31) {
#pragma unroll
            for (int i = 0; i < 2; ++i) {
                int r  = wid * 2 + i;
                int kk = r >> 2, cc = r & 3;
                const float* src = Kb + ((size_t)((t + 1) * 64 + 2 * p + kk)) * 32 + h * 16 + cc * 4;
                gload_lds16(src, &Kl[buf ^ 1][r * 256]);
            }
        }
        float pA0 = 0.f, pA1 = 0.f, pB0 = 0.f, pB1 = 0.f;
#pragma unroll
        for (int c = 0; c < 4; ++c) {
            float4 kva = *(const float4*)&Kl[buf][c * 256 + lane * 4];         // key 2p
            float4 kvb = *(const float4*)&Kl[buf][(4 + c) * 256 + lane * 4];   // key 2p+1
            pA0 += qa[c*4+0]*kva.x + qa[c*4+1]*kva.y + qa[c*4+2]*kva.z + qa[c*4+3]*kva.w;
            pA1 += qc[c*4+0]*kva.x + qc[c*4+1]*kva.y + qc[c*4+2]*kva.z + qc[c*4+3]*kva.w;
            pB0 += qa[c*4+0]*kvb.x + qa[c*4+1]*kvb.y + qa[c*4+2]*kvb.z + qa[c*4+3]*kvb.w;
            pB1 += qc[c*4+0]*kvb.x + qc[c*4+1]*kvb.y + qc[c*4+2]*kvb.z + qc[c*4+3]*kvb.w;
        }
        float fA0 = pA0 + __shfl_xor(pA0, 32);
        float fB0 = pB0 + __shfl_xor(pB0, 32);
        float fA1 = pA1 + __shfl_xor(pA1, 32);
        float fB1 = pB1 + __shfl_xor(pB1, 32);
        k0[t] = sortkey(h ? fB0 : fA0);     // lane keeps key 2p + h of tile t
        k1[t] = sortkey(h ? fB1 : fA1);
        asm volatile("s_waitcnt vmcnt(0)" ::: "memory");
        __syncthreads();
        buf ^= 1;
    }

    // per-wave select + softmax + PV (waves independent from here on)
    SELECT_ROW(k0, 0)
    SELECT_ROW(k1, 1)
}

// ---------------------------------------------------------------------------
// Residual add + LayerNorm over 256, in place into h. One wave per row.
// ---------------------------------------------------------------------------
__global__ __launch_bounds__(64) void k_addln(float* __restrict__ h,
                                              const float* __restrict__ a,
                                              const float* __restrict__ g,
                                              const float* __restrict__ bb) {
    int row = blockIdx.x, lane = threadIdx.x;
    float4 hv = *(const float4*)&h[(size_t)row * D_MODEL + lane * 4];
    float4 av = *(const float4*)&a[(size_t)row * D_MODEL + lane * 4];
    float x0 = hv.x + av.x, x1 = hv.y + av.y, x2 = hv.z + av.z, x3 = hv.w + av.w;
    float s = x0 + x1 + x2 + x3;
#pragma unroll
    for (int off = 32; off >= 1; off >>= 1) s += __shfl_xor(s, off);
    float mean = s * (1.0f / 256.0f);
    float d0 = x0 - mean, d1 = x1 - mean, d2 = x2 - mean, d3 = x3 - mean;
    float vs = d0 * d0 + d1 * d1 + d2 * d2 + d3 * d3;
#pragma unroll
    for (int off = 32; off >= 1; off >>= 1) vs += __shfl_xor(vs, off);
    float inv = rsqrtf(vs * (1.0f / 256.0f) + 1e-5f);
    float4 gv = *(const float4*)&g[lane * 4];
    float4 bv = *(const float4*)&bb[lane * 4];
    float4 o;
    o.x = d0 * inv * gv.x + bv.x;
    o.y = d1 * inv * gv.y + bv.y;
    o.z = d2 * inv * gv.z + bv.z;
    o.w = d3 * inv * gv.w + bv.w;
    *(float4*)&h[(size_t)row * D_MODEL + lane * 4] = o;
}

// ---------------------------------------------------------------------------
// Decoder head
// ---------------------------------------------------------------------------
__global__ __launch_bounds__(64) void k_dec(const float* __restrict__ h,
                                            const float* __restrict__ w,
                                            const float* __restrict__ b,
                                            float* __restrict__ out) {
    int row = blockIdx.x, lane = threadIdx.x;
    int c = lane & 7, part = lane >> 3;   // 8 parts x 32 dims
    float acc = 0.f;
    int d0 = part * 32;
#pragma unroll
    for (int dd = 0; dd < 32; ++dd) acc += h[(size_t)row * D_MODEL + d0 + dd] * w[(d0 + dd) * 8 + c];
    acc += __shfl_xor(acc, 8);
    acc += __shfl_xor(acc, 16);
    acc += __shfl_xor(acc, 32);
    if (lane < 8) out[(size_t)row * 8 + c] = acc + b[c];
}

// ---------------------------------------------------------------------------
extern "C" void kernel_launch(void* const* d_in, const int* in_sizes, int n_in,
                              void* d_out, int out_size, void* d_ws, size_t ws_size,
                              hipStream_t stream) {
    const float* x     = (const float*)d_in[0];
    const float* emb_w = (const float*)d_in[1];
    const float* emb_b = (const float*)d_in[2];
    const float* wq    = (const float*)d_in[3];
    const float* bq    = (const float*)d_in[4];
    const float* wk    = (const float*)d_in[5];
    const float* bk    = (const float*)d_in[6];
    const float* wv    = (const float*)d_in[7];
    const float* bv    = (const float*)d_in[8];
    const float* wo    = (const float*)d_in[9];
    const float* bo    = (const float*)d_in[10];
    const float* ln1_g = (const float*)d_in[11];
    const float* ln1_b = (const float*)d_in[12];
    const float* ln2_g = (const float*)d_in[13];
    const float* ln2_b = (const float*)d_in[14];
    const float* ff1_w = (const float*)d_in[15];
    const float* ff1_b = (const float*)d_in[16];
    const float* ff2_w = (const float*)d_in[17];
    const float* ff2_b = (const float*)d_in[18];
    const float* dec_w = (const float*)d_in[19];
    const float* dec_b = (const float*)d_in[20];

    float* ws   = (float*)d_ws;
    float* h    = ws;                      // 4096*256   = 1M floats
    float* qb   = h    + (1 << 20);
    float* kb   = qb   + (1 << 20);
    float* vb   = kb   + (1 << 20);
    float* ctxb = vb   + (1 << 20);
    float* tmp  = ctxb + (1 << 20);
    float* ffb  = tmp  + (1 << 20);        // 4096*1024 = 4M

    k_embed<<<ROWS, 256, 0, stream>>>(x, emb_w, emb_b, h);

    for (int l = 0; l < 2; ++l) {
        const float* wql = wq + (size_t)l * 65536;  const float* bql = bq + l * 256;
        const float* wkl = wk + (size_t)l * 65536;  const float* bkl = bk + l * 256;
        const float* wvl = wv + (size_t)l * 65536;  const float* bvl = bv + l * 256;
        const float* wol = wo + (size_t)l * 65536;  const float* bol = bo + l * 256;

        dim3 g4(64, 4);
        k_gemm<2><<<g4, 256, 0, stream>>>(h, wql, bql, qb, ROWS, 256, 256);
        k_gemm<2><<<g4, 256, 0, stream>>>(h, wkl, bkl, kb, ROWS, 256, 256);
        k_gemm<2><<<g4, 256, 0, stream>>>(h, wvl, bvl, vb, ROWS, 256, 256);

        k_attn<<<NHEAD * BATCH * 256, 256, 0, stream>>>(qb, kb, vb, ctxb);

        k_gemm<0><<<g4, 256, 0, stream>>>(ctxb, wol, bol, tmp, ROWS, 256, 256);
        k_addln<<<ROWS, 64, 0, stream>>>(h, tmp, ln1_g + l * 256, ln1_b + l * 256);

        dim3 g16(64, 16);
        k_gemm<1><<<g16, 256, 0, stream>>>(h, ff1_w + (size_t)l * 262144, ff1_b + l * 1024,
                                           ffb, ROWS, D_FF, 256);
        k_gemm<0><<<g4, 256, 0, stream>>>(ffb, ff2_w + (size_t)l * 262144, ff2_b + l * 256,
                                          tmp, ROWS, 256, D_FF);
        k_addln<<<ROWS, 64, 0, stream>>>(h, tmp, ln2_g + l * 256, ln2_b + l * 256);
    }

    k_dec<<<ROWS, 64, 0, stream>>>(h, dec_w, dec_b, (float*)d_out);
}

// Round 6
// 1652.452 us; speedup vs baseline: 2.4556x; 1.5353x over previous
//
#include <hip/hip_runtime.h>
#include <math.h>

#define D_MODEL 256
#define NHEAD   8
#define D_K     32
#define LSEQ    2048
#define BATCH   2
#define ROWS    (BATCH * LSEQ)   // 4096
#define D_FF    1024
#define UTOP    38

// ---------------------------------------------------------------------------
// Embedding + positional encoding
// ---------------------------------------------------------------------------
__global__ __launch_bounds__(256) void k_embed(const float* __restrict__ x,
                                               const float* __restrict__ w,
                                               const float* __restrict__ b,
                                               float* __restrict__ h) {
    int row = blockIdx.x;           // b*L + l
    int l   = row & (LSEQ - 1);
    int d   = threadIdx.x;
    __shared__ float xs[32];
    if (d < 32) xs[d] = x[row * 32 + d];
    __syncthreads();
    float acc = 0.f;
#pragma unroll
    for (int i = 0; i < 32; ++i) acc += xs[i] * w[i * D_MODEL + d];
    acc = (acc + b[d]) * 16.0f;     // sqrt(256)
    int m = d >> 1;
    float div = expf(-(float)(2 * m) * (9.210340371976184f / 256.0f)); // ln(1e4)/256
    float ang = (float)l * div;
    float pe = (d & 1) ? cosf(ang) : sinf(ang);
    h[row * D_MODEL + d] = acc + pe;
}

// ---------------------------------------------------------------------------
// Generic fp32 tiled GEMM: C = A[M,K] @ W[K,N] + bias
// MODE 0: plain   MODE 1: relu   MODE 2: scatter to q/k/v layout [B,H,L,32]
// ---------------------------------------------------------------------------
template <int MODE>
__global__ __launch_bounds__(256) void k_gemm(const float* __restrict__ A,
                                              const float* __restrict__ W,
                                              const float* __restrict__ bias,
                                              float* __restrict__ C,
                                              int M, int N, int K) {
    __shared__ float As[16][68];
    __shared__ float Ws[16][68];
    const int t  = threadIdx.x;
    const int tx = t & 15, ty = t >> 4;
    const int m0 = blockIdx.x * 64, n0 = blockIdx.y * 64;
    float acc[4][4] = {};
    for (int k0 = 0; k0 < K; k0 += 16) {
        {
            int mr = t >> 2, kc = (t & 3) * 4;
            float4 av = *(const float4*)&A[(size_t)(m0 + mr) * K + k0 + kc];
            As[kc + 0][mr] = av.x; As[kc + 1][mr] = av.y;
            As[kc + 2][mr] = av.z; As[kc + 3][mr] = av.w;
            int kr = t >> 4, nc = (t & 15) * 4;
            *(float4*)&Ws[kr][nc] = *(const float4*)&W[(size_t)(k0 + kr) * N + n0 + nc];
        }
        __syncthreads();
#pragma unroll
        for (int k = 0; k < 16; ++k) {
            float4 a4 = *(const float4*)&As[k][ty * 4];
            float4 w4 = *(const float4*)&Ws[k][tx * 4];
            float av[4] = {a4.x, a4.y, a4.z, a4.w};
            float wv[4] = {w4.x, w4.y, w4.z, w4.w};
#pragma unroll
            for (int i = 0; i < 4; ++i)
#pragma unroll
                for (int j = 0; j < 4; ++j) acc[i][j] += av[i] * wv[j];
        }
        __syncthreads();
    }
#pragma unroll
    for (int i = 0; i < 4; ++i) {
        int row = m0 + ty * 4 + i;
#pragma unroll
        for (int j = 0; j < 4; ++j) {
            int col = n0 + tx * 4 + j;
            float v = acc[i][j] + bias[col];
            if (MODE == 1) v = fmaxf(v, 0.f);
            if (MODE == 2) {
                int bb = row >> 11, ll = row & (LSEQ - 1);
                int hh = col >> 5, dd = col & 31;
                C[(((size_t)(bb * NHEAD + hh) * LSEQ) + ll) * D_K + dd] = v;
            } else {
                C[(size_t)row * N + col] = v;
            }
        }
    }
}

// ---------------------------------------------------------------------------
// Fused ProbSparse attention, v5 — spill-proof by construction.
// Block = 4 waves (256 thr); each wave owns 4 query rows of one (b,h).
// Scores are NOT kept in registers: written per-tile to an LDS score buffer
// (order-preserving uint32 sortkeys, 8 KB/row, 16 rows = 128 KB).
// K staged via global_load_lds (double-buffered, read-order-linear layout,
// conflict-free ds_read_b128). d-split: lanes 0..31 use dims 0..15,
// lanes 32..63 dims 16..31; half-dots combined with one shfl_xor(32).
// Exact top-38 via wave-private 4x8-bit radix select reading scores from LDS.
// ---------------------------------------------------------------------------
__device__ __forceinline__ unsigned int sortkey(float f) {
    unsigned int u = __float_as_uint(f);
    return (u & 0x80000000u) ? ~u : (u | 0x80000000u);
}
__device__ __forceinline__ float key2f(unsigned int u) {
    unsigned int b = (u & 0x80000000u) ? (u ^ 0x80000000u) : ~u;
    return __uint_as_float(b);
}
__device__ __forceinline__ void gload_lds16(const float* src, float* ldsDst) {
    __builtin_amdgcn_global_load_lds(
        (const __attribute__((address_space(1))) unsigned int*)src,
        (__attribute__((address_space(3))) unsigned int*)ldsDst,
        16, 0, 0);
}

__global__ __launch_bounds__(256, 1) void k_attn(const float* __restrict__ Q,
                                                 const float* __restrict__ Kt,
                                                 const float* __restrict__ Vt,
                                                 float* __restrict__ ctxb) {
    __shared__ unsigned int sc[4][4][2048];   // [wave][row][key] 128 KB
    __shared__ float        Kl[2][2048];      // 16 KB (double-buffered K tile)
    __shared__ int          hist[4][256];     // 4 KB
    __shared__ float        lv[4][96];        // 1.5 KB
    __shared__ int          li[4][96];        // 1.5 KB
    __shared__ int          lcnt[4];

    const int tid   = threadIdx.x;
    const int lane  = tid & 63;
    const int wid   = tid >> 6;
    const int bh    = blockIdx.x >> 7;        // 16 bh x 128 chunks
    const int chunk = blockIdx.x & 127;
    const int row0  = chunk * 16 + wid * 4;   // 4 rows per wave
    const int b     = bh >> 3, hh = bh & 7;
    const int h     = lane >> 5;              // d-half owned by this lane
    const int p     = lane & 31;

    const float* Kb = Kt + (size_t)bh * LSEQ * D_K;
    const float* Vb = Vt + (size_t)bh * LSEQ * D_K;
    const float* qp = Q + ((size_t)bh * LSEQ + row0) * D_K;

    const float scale = 0.17677669529663687f; // 1/sqrt(32)
    float q0[16], q1[16], q2[16], q3[16];
#pragma unroll
    for (int i = 0; i < 16; ++i) {
        q0[i] = qp[      h * 16 + i] * scale;
        q1[i] = qp[32  + h * 16 + i] * scale;
        q2[i] = qp[64  + h * 16 + i] * scale;
        q3[i] = qp[96  + h * 16 + i] * scale;
    }

    // prologue: stage tile 0 (keys 0..63). Granule r=wid*2+i, r in 0..7:
    // holds dim-chunk (r&3) of key 2p + (r>>2), half h; LDS dst lane-linear.
    {
#pragma unroll
        for (int i = 0; i < 2; ++i) {
            int r  = wid * 2 + i;
            int kk = r >> 2, cc = r & 3;
            const float* src = Kb + ((size_t)(2 * p + kk)) * 32 + h * 16 + cc * 4;
            gload_lds16(src, &Kl[0][r * 256]);
        }
    }
    asm volatile("s_waitcnt vmcnt(0)" ::: "memory");
    __syncthreads();

    int buf = 0;
    for (int t = 0; t < 32; ++t) {
        if (t < 31) {
#pragma unroll
            for (int i = 0; i < 2; ++i) {
                int r  = wid * 2 + i;
                int kk = r >> 2, cc = r & 3;
                const float* src = Kb + ((size_t)((t + 1) * 64 + 2 * p + kk)) * 32 + h * 16 + cc * 4;
                gload_lds16(src, &Kl[buf ^ 1][r * 256]);
            }
        }
        float a0 = 0.f, a1 = 0.f, a2 = 0.f, a3 = 0.f;   // key 2p half-dots
        float e0 = 0.f, e1 = 0.f, e2 = 0.f, e3 = 0.f;   // key 2p+1 half-dots
#pragma unroll
        for (int c = 0; c < 4; ++c) {
            float4 kva = *(const float4*)&Kl[buf][c * 256 + lane * 4];        // key 2p
            float4 kvb = *(const float4*)&Kl[buf][(4 + c) * 256 + lane * 4];  // key 2p+1
            a0 += q0[c*4+0]*kva.x + q0[c*4+1]*kva.y + q0[c*4+2]*kva.z + q0[c*4+3]*kva.w;
            a1 += q1[c*4+0]*kva.x + q1[c*4+1]*kva.y + q1[c*4+2]*kva.z + q1[c*4+3]*kva.w;
            a2 += q2[c*4+0]*kva.x + q2[c*4+1]*kva.y + q2[c*4+2]*kva.z + q2[c*4+3]*kva.w;
            a3 += q3[c*4+0]*kva.x + q3[c*4+1]*kva.y + q3[c*4+2]*kva.z + q3[c*4+3]*kva.w;
            e0 += q0[c*4+0]*kvb.x + q0[c*4+1]*kvb.y + q0[c*4+2]*kvb.z + q0[c*4+3]*kvb.w;
            e1 += q1[c*4+0]*kvb.x + q1[c*4+1]*kvb.y + q1[c*4+2]*kvb.z + q1[c*4+3]*kvb.w;
            e2 += q2[c*4+0]*kvb.x + q2[c*4+1]*kvb.y + q2[c*4+2]*kvb.z + q2[c*4+3]*kvb.w;
            e3 += q3[c*4+0]*kvb.x + q3[c*4+1]*kvb.y + q3[c*4+2]*kvb.z + q3[c*4+3]*kvb.w;
        }
        // combine halves; lane keeps key 2p+h for each row; write sortkey to LDS
        {
            float fa = a0 + __shfl_xor(a0, 32);
            float fe = e0 + __shfl_xor(e0, 32);
            sc[wid][0][t * 64 + 2 * p + h] = sortkey(h ? fe : fa);
            fa = a1 + __shfl_xor(a1, 32);
            fe = e1 + __shfl_xor(e1, 32);
            sc[wid][1][t * 64 + 2 * p + h] = sortkey(h ? fe : fa);
            fa = a2 + __shfl_xor(a2, 32);
            fe = e2 + __shfl_xor(e2, 32);
            sc[wid][2][t * 64 + 2 * p + h] = sortkey(h ? fe : fa);
            fa = a3 + __shfl_xor(a3, 32);
            fe = e3 + __shfl_xor(e3, 32);
            sc[wid][3][t * 64 + 2 * p + h] = sortkey(h ? fe : fa);
        }
        asm volatile("s_waitcnt vmcnt(0)" ::: "memory");
        __syncthreads();
        buf ^= 1;
    }

    // per-wave select + softmax + PV for its 4 rows (waves independent)
    for (int rr = 0; rr < 4; ++rr) {
        const unsigned int* S = &sc[wid][rr][0];

        unsigned int mk = 0;
#pragma unroll
        for (int j = 0; j < 32; ++j) mk = max(mk, S[j * 64 + lane]);
#pragma unroll
        for (int off = 32; off >= 1; off >>= 1) {
            unsigned int o = (unsigned int)__shfl_xor((int)mk, off);
            if (o > mk) mk = o;
        }
        const float rowmax = key2f(mk);

        unsigned int prefix = 0;
        int need = UTOP;
#pragma unroll
        for (int pass = 0; pass < 4; ++pass) {
            const int sh = 24 - pass * 8;
            *(int4*)&hist[wid][lane * 4] = make_int4(0, 0, 0, 0);
#pragma unroll
            for (int j = 0; j < 32; ++j) {
                unsigned int key = S[j * 64 + lane];
                bool msk = (pass == 0) || ((key >> (sh + 8)) == (prefix >> (sh + 8)));
                if (msk) atomicAdd(&hist[wid][(key >> sh) & 255], 1);
            }
            int4 hb = *(const int4*)&hist[wid][lane * 4];
            int csum = hb.x + hb.y + hb.z + hb.w;
            int suf = csum;
#pragma unroll
            for (int off = 1; off < 64; off <<= 1) {
                int o = __shfl_down(suf, off);
                if (lane + off < 64) suf += o;
            }
            int above = suf - csum;   // keys in strictly-higher bins
            bool found = (above < need) && (above + csum >= need);
            unsigned int cp = 0; int cn = 0;
            if (found) {
                int cum = above, dd, na;
                if (cum + hb.w >= need)      { dd = 3; na = cum; }
                else { cum += hb.w;
                if (cum + hb.z >= need)      { dd = 2; na = cum; }
                else { cum += hb.z;
                if (cum + hb.y >= need)      { dd = 1; na = cum; }
                else { cum += hb.y;            dd = 0; na = cum; } } }
                cp = prefix | ((unsigned int)(lane * 4 + dd) << sh);
                cn = need - na;
            }
            unsigned long long bal = __ballot(found);
            int wl = (int)(__ffsll(bal) - 1);
            prefix = (unsigned int)__shfl((int)cp, wl);
            need   = __shfl(cn, wl);
        }
        const unsigned int thrkey = prefix;   // exact 38th-largest key

        if (lane == 0) lcnt[wid] = 0;
#pragma unroll
        for (int j = 0; j < 32; ++j) {
            unsigned int key = S[j * 64 + lane];
            if (key >= thrkey) {
                int slot = atomicAdd(&lcnt[wid], 1);
                if (slot < 96) {
                    lv[wid][slot] = key2f(key);
                    li[wid][slot] = j * 64 + lane;
                }
            }
        }
        int cnt = lcnt[wid]; if (cnt > 96) cnt = 96;

        float psum = 0.f;
        for (int i = lane; i < cnt; i += 64) psum += expf(lv[wid][i] - rowmax);
#pragma unroll
        for (int off = 32; off >= 1; off >>= 1) psum += __shfl_xor(psum, off);
        float inv = 1.0f / psum;

        int dcol = lane & 31, hs = lane >> 5;
        float acc = 0.f;
        for (int i = hs; i < cnt; i += 2)
            acc += expf(lv[wid][i] - rowmax) * Vb[(size_t)li[wid][i] * D_K + dcol];
        acc += __shfl_xor(acc, 32);
        if (lane < 32)
            ctxb[((size_t)(b * LSEQ) + row0 + rr) * D_MODEL + hh * D_K + dcol] = acc * inv;
    }
}

// ---------------------------------------------------------------------------
// Residual add + LayerNorm over 256, in place into h. One wave per row.
// ---------------------------------------------------------------------------
__global__ __launch_bounds__(64) void k_addln(float* __restrict__ h,
                                              const float* __restrict__ a,
                                              const float* __restrict__ g,
                                              const float* __restrict__ bb) {
    int row = blockIdx.x, lane = threadIdx.x;
    float4 hv = *(const float4*)&h[(size_t)row * D_MODEL + lane * 4];
    float4 av = *(const float4*)&a[(size_t)row * D_MODEL + lane * 4];
    float x0 = hv.x + av.x, x1 = hv.y + av.y, x2 = hv.z + av.z, x3 = hv.w + av.w;
    float s = x0 + x1 + x2 + x3;
#pragma unroll
    for (int off = 32; off >= 1; off >>= 1) s += __shfl_xor(s, off);
    float mean = s * (1.0f / 256.0f);
    float d0 = x0 - mean, d1 = x1 - mean, d2 = x2 - mean, d3 = x3 - mean;
    float vs = d0 * d0 + d1 * d1 + d2 * d2 + d3 * d3;
#pragma unroll
    for (int off = 32; off >= 1; off >>= 1) vs += __shfl_xor(vs, off);
    float inv = rsqrtf(vs * (1.0f / 256.0f) + 1e-5f);
    float4 gv = *(const float4*)&g[lane * 4];
    float4 bv = *(const float4*)&bb[lane * 4];
    float4 o;
    o.x = d0 * inv * gv.x + bv.x;
    o.y = d1 * inv * gv.y + bv.y;
    o.z = d2 * inv * gv.z + bv.z;
    o.w = d3 * inv * gv.w + bv.w;
    *(float4*)&h[(size_t)row * D_MODEL + lane * 4] = o;
}

// ---------------------------------------------------------------------------
// Decoder head
// ---------------------------------------------------------------------------
__global__ __launch_bounds__(64) void k_dec(const float* __restrict__ h,
                                            const float* __restrict__ w,
                                            const float* __restrict__ b,
                                            float* __restrict__ out) {
    int row = blockIdx.x, lane = threadIdx.x;
    int c = lane & 7, part = lane >> 3;   // 8 parts x 32 dims
    float acc = 0.f;
    int d0 = part * 32;
#pragma unroll
    for (int dd = 0; dd < 32; ++dd) acc += h[(size_t)row * D_MODEL + d0 + dd] * w[(d0 + dd) * 8 + c];
    acc += __shfl_xor(acc, 8);
    acc += __shfl_xor(acc, 16);
    acc += __shfl_xor(acc, 32);
    if (lane < 8) out[(size_t)row * 8 + c] = acc + b[c];
}

// ---------------------------------------------------------------------------
extern "C" void kernel_launch(void* const* d_in, const int* in_sizes, int n_in,
                              void* d_out, int out_size, void* d_ws, size_t ws_size,
                              hipStream_t stream) {
    const float* x     = (const float*)d_in[0];
    const float* emb_w = (const float*)d_in[1];
    const float* emb_b = (const float*)d_in[2];
    const float* wq    = (const float*)d_in[3];
    const float* bq    = (const float*)d_in[4];
    const float* wk    = (const float*)d_in[5];
    const float* bk    = (const float*)d_in[6];
    const float* wv    = (const float*)d_in[7];
    const float* bv    = (const float*)d_in[8];
    const float* wo    = (const float*)d_in[9];
    const float* bo    = (const float*)d_in[10];
    const float* ln1_g = (const float*)d_in[11];
    const float* ln1_b = (const float*)d_in[12];
    const float* ln2_g = (const float*)d_in[13];
    const float* ln2_b = (const float*)d_in[14];
    const float* ff1_w = (const float*)d_in[15];
    const float* ff1_b = (const float*)d_in[16];
    const float* ff2_w = (const float*)d_in[17];
    const float* ff2_b = (const float*)d_in[18];
    const float* dec_w = (const float*)d_in[19];
    const float* dec_b = (const float*)d_in[20];

    float* ws   = (float*)d_ws;
    float* h    = ws;                      // 4096*256   = 1M floats
    float* qb   = h    + (1 << 20);
    float* kb   = qb   + (1 << 20);
    float* vb   = kb   + (1 << 20);
    float* ctxb = vb   + (1 << 20);
    float* tmp  = ctxb + (1 << 20);
    float* ffb  = tmp  + (1 << 20);        // 4096*1024 = 4M

    k_embed<<<ROWS, 256, 0, stream>>>(x, emb_w, emb_b, h);

    for (int l = 0; l < 2; ++l) {
        const float* wql = wq + (size_t)l * 65536;  const float* bql = bq + l * 256;
        const float* wkl = wk + (size_t)l * 65536;  const float* bkl = bk + l * 256;
        const float* wvl = wv + (size_t)l * 65536;  const float* bvl = bv + l * 256;
        const float* wol = wo + (size_t)l * 65536;  const float* bol = bo + l * 256;

        dim3 g4(64, 4);
        k_gemm<2><<<g4, 256, 0, stream>>>(h, wql, bql, qb, ROWS, 256, 256);
        k_gemm<2><<<g4, 256, 0, stream>>>(h, wkl, bkl, kb, ROWS, 256, 256);
        k_gemm<2><<<g4, 256, 0, stream>>>(h, wvl, bvl, vb, ROWS, 256, 256);

        k_attn<<<NHEAD * BATCH * 128, 256, 0, stream>>>(qb, kb, vb, ctxb);

        k_gemm<0><<<g4, 256, 0, stream>>>(ctxb, wol, bol, tmp, ROWS, 256, 256);
        k_addln<<<ROWS, 64, 0, stream>>>(h, tmp, ln1_g + l * 256, ln1_b + l * 256);

        dim3 g16(64, 16);
        k_gemm<1><<<g16, 256, 0, stream>>>(h, ff1_w + (size_t)l * 262144, ff1_b + l * 1024,
                                           ffb, ROWS, D_FF, 256);
        k_gemm<0><<<g4, 256, 0, stream>>>(ffb, ff2_w + (size_t)l * 262144, ff2_b + l * 256,
                                          tmp, ROWS, 256, D_FF);
        k_addln<<<ROWS, 64, 0, stream>>>(h, tmp, ln2_g + l * 256, ln2_b + l * 256);
    }

    k_dec<<<ROWS, 64, 0, stream>>>(h, dec_w, dec_b, (float*)d_out);
}

// Round 7
// 1191.508 us; speedup vs baseline: 3.4056x; 1.3869x over previous
//
#include <hip/hip_runtime.h>
#include <math.h>

#define D_MODEL 256
#define NHEAD   8
#define D_K     32
#define LSEQ    2048
#define BATCH   2
#define ROWS    (BATCH * LSEQ)   // 4096
#define D_FF    1024
#define UTOP    38
#define CAP     224

// ---------------------------------------------------------------------------
// Embedding + positional encoding
// ---------------------------------------------------------------------------
__global__ __launch_bounds__(256) void k_embed(const float* __restrict__ x,
                                               const float* __restrict__ w,
                                               const float* __restrict__ b,
                                               float* __restrict__ h) {
    int row = blockIdx.x;           // b*L + l
    int l   = row & (LSEQ - 1);
    int d   = threadIdx.x;
    __shared__ float xs[32];
    if (d < 32) xs[d] = x[row * 32 + d];
    __syncthreads();
    float acc = 0.f;
#pragma unroll
    for (int i = 0; i < 32; ++i) acc += xs[i] * w[i * D_MODEL + d];
    acc = (acc + b[d]) * 16.0f;     // sqrt(256)
    int m = d >> 1;
    float div = expf(-(float)(2 * m) * (9.210340371976184f / 256.0f)); // ln(1e4)/256
    float ang = (float)l * div;
    float pe = (d & 1) ? cosf(ang) : sinf(ang);
    h[row * D_MODEL + d] = acc + pe;
}

// ---------------------------------------------------------------------------
// Generic fp32 tiled GEMM: C = A[M,K] @ W[K,N] + bias
// MODE 0: plain   MODE 1: relu   MODE 2: scatter to q/k/v layout [B,H,L,32]
// ---------------------------------------------------------------------------
template <int MODE>
__global__ __launch_bounds__(256) void k_gemm(const float* __restrict__ A,
                                              const float* __restrict__ W,
                                              const float* __restrict__ bias,
                                              float* __restrict__ C,
                                              int M, int N, int K) {
    __shared__ float As[16][68];
    __shared__ float Ws[16][68];
    const int t  = threadIdx.x;
    const int tx = t & 15, ty = t >> 4;
    const int m0 = blockIdx.x * 64, n0 = blockIdx.y * 64;
    float acc[4][4] = {};
    for (int k0 = 0; k0 < K; k0 += 16) {
        {
            int mr = t >> 2, kc = (t & 3) * 4;
            float4 av = *(const float4*)&A[(size_t)(m0 + mr) * K + k0 + kc];
            As[kc + 0][mr] = av.x; As[kc + 1][mr] = av.y;
            As[kc + 2][mr] = av.z; As[kc + 3][mr] = av.w;
            int kr = t >> 4, nc = (t & 15) * 4;
            *(float4*)&Ws[kr][nc] = *(const float4*)&W[(size_t)(k0 + kr) * N + n0 + nc];
        }
        __syncthreads();
#pragma unroll
        for (int k = 0; k < 16; ++k) {
            float4 a4 = *(const float4*)&As[k][ty * 4];
            float4 w4 = *(const float4*)&Ws[k][tx * 4];
            float av[4] = {a4.x, a4.y, a4.z, a4.w};
            float wv[4] = {w4.x, w4.y, w4.z, w4.w};
#pragma unroll
            for (int i = 0; i < 4; ++i)
#pragma unroll
                for (int j = 0; j < 4; ++j) acc[i][j] += av[i] * wv[j];
        }
        __syncthreads();
    }
#pragma unroll
    for (int i = 0; i < 4; ++i) {
        int row = m0 + ty * 4 + i;
#pragma unroll
        for (int j = 0; j < 4; ++j) {
            int col = n0 + tx * 4 + j;
            float v = acc[i][j] + bias[col];
            if (MODE == 1) v = fmaxf(v, 0.f);
            if (MODE == 2) {
                int bb = row >> 11, ll = row & (LSEQ - 1);
                int hh = col >> 5, dd = col & 31;
                C[(((size_t)(bb * NHEAD + hh) * LSEQ) + ll) * D_K + dd] = v;
            } else {
                C[(size_t)row * N + col] = v;
            }
        }
    }
}

// ---------------------------------------------------------------------------
// Fused ProbSparse attention, v6 — pivot select, no score storage.
// Block = 4 waves (256 thr); each wave owns 8 query rows of one (b,h).
// Pass 1: QK dots (K in double-buffered LDS via global_load_lds), track only
//   per-lane per-row max. Pivot = 38th-largest of the 64 lane-maxes (bitonic
//   sort over shfl) -> guaranteed >= 38 keys above pivot, expected ~55.
// Pass 2: recompute dots (bit-identical), push candidates >= pivot into small
//   per-row LDS lists (CAP 224).
// Exact 38th-largest threshold via 4x8-bit radix select over the small list,
// then masked softmax + PV gather. Reference tie semantics (>= thr) exact.
// ---------------------------------------------------------------------------
__device__ __forceinline__ unsigned int sortkey(float f) {
    unsigned int u = __float_as_uint(f);
    return (u & 0x80000000u) ? ~u : (u | 0x80000000u);
}
__device__ __forceinline__ float key2f(unsigned int u) {
    unsigned int b = (u & 0x80000000u) ? (u ^ 0x80000000u) : ~u;
    return __uint_as_float(b);
}
__device__ __forceinline__ void gload_lds16(const float* src, float* ldsDst) {
    __builtin_amdgcn_global_load_lds(
        (const __attribute__((address_space(1))) unsigned int*)src,
        (__attribute__((address_space(3))) unsigned int*)ldsDst,
        16, 0, 0);
}

__global__ __launch_bounds__(256, 2) void k_attn(const float* __restrict__ Q,
                                                 const float* __restrict__ Kt,
                                                 const float* __restrict__ Vt,
                                                 float* __restrict__ ctxb) {
    __shared__ float        Kl[2][2048];        // 16 KB   K tile double-buffer
    __shared__ unsigned int lvk[4][8][CAP];     // 28.7 KB candidate keys
    __shared__ int          lix[4][8][CAP];     // 28.7 KB candidate indices
    __shared__ int          hist[4][256];       // 4 KB    radix histogram
    __shared__ int          lcnt[4][8];
    __shared__ unsigned int tpv[4][8];          // pivot / rowmax keys
    __shared__ unsigned int rmx[4][8];

    const int tid   = threadIdx.x;
    const int lane  = tid & 63;
    const int wid   = tid >> 6;
    const int bh    = blockIdx.x >> 6;          // 16 bh x 64 chunks
    const int chunk = blockIdx.x & 63;
    const int row0  = chunk * 32 + wid * 8;     // 8 rows per wave
    const int b     = bh >> 3, hh = bh & 7;
    const int h     = lane >> 5;                // d-half owned by this lane
    const int p     = lane & 31;

    const float* Kb = Kt + (size_t)bh * LSEQ * D_K;
    const float* Vb = Vt + (size_t)bh * LSEQ * D_K;
    const float* qp = Q + ((size_t)bh * LSEQ + row0) * D_K;

    const float scale = 0.17677669529663687f;   // 1/sqrt(32)
    float q[8][16];
#pragma unroll
    for (int r = 0; r < 8; ++r)
#pragma unroll
        for (int i = 0; i < 16; ++i)
            q[r][i] = qp[r * 32 + h * 16 + i] * scale;

    if (lane < 8) lcnt[wid][lane] = 0;

    // ---- PASS 1: dots, track lane-max per row --------------------------
    unsigned int lmax[8];
#pragma unroll
    for (int r = 0; r < 8; ++r) lmax[r] = 0u;

#pragma unroll
    for (int i = 0; i < 2; ++i) {
        int r  = wid * 2 + i;
        int kk = r >> 2, cc = r & 3;
        gload_lds16(Kb + ((size_t)(2 * p + kk)) * 32 + h * 16 + cc * 4, &Kl[0][r * 256]);
    }
    asm volatile("s_waitcnt vmcnt(0)" ::: "memory");
    __syncthreads();

    for (int t = 0; t < 32; ++t) {
        const int buf = t & 1;
        if (t < 31) {
#pragma unroll
            for (int i = 0; i < 2; ++i) {
                int r  = wid * 2 + i;
                int kk = r >> 2, cc = r & 3;
                gload_lds16(Kb + ((size_t)((t + 1) * 64 + 2 * p + kk)) * 32 + h * 16 + cc * 4,
                            &Kl[buf ^ 1][r * 256]);
            }
        }
        float a[8], e[8];
#pragma unroll
        for (int r = 0; r < 8; ++r) { a[r] = 0.f; e[r] = 0.f; }
#pragma unroll
        for (int c = 0; c < 4; ++c) {
            float4 kva = *(const float4*)&Kl[buf][c * 256 + lane * 4];        // key 2p
            float4 kvb = *(const float4*)&Kl[buf][(4 + c) * 256 + lane * 4];  // key 2p+1
#pragma unroll
            for (int r = 0; r < 8; ++r) {
                a[r] += q[r][c*4+0]*kva.x + q[r][c*4+1]*kva.y + q[r][c*4+2]*kva.z + q[r][c*4+3]*kva.w;
                e[r] += q[r][c*4+0]*kvb.x + q[r][c*4+1]*kvb.y + q[r][c*4+2]*kvb.z + q[r][c*4+3]*kvb.w;
            }
        }
#pragma unroll
        for (int r = 0; r < 8; ++r) {
            float fa = a[r] + __shfl_xor(a[r], 32);
            float fe = e[r] + __shfl_xor(e[r], 32);
            unsigned int k = sortkey(h ? fe : fa);   // lane owns key 2p+h
            if (k > lmax[r]) lmax[r] = k;
        }
        asm volatile("s_waitcnt vmcnt(0)" ::: "memory");
        __syncthreads();
    }

    // ---- pivot per row: bitonic-sort 64 lane-maxes (ascending) ---------
#pragma unroll
    for (int r = 0; r < 8; ++r) {
        unsigned int v = lmax[r];
#pragma unroll
        for (int k = 2; k <= 64; k <<= 1) {
#pragma unroll
            for (int j = k >> 1; j >= 1; j >>= 1) {
                unsigned int pv = (unsigned int)__shfl_xor((int)v, j);
                bool lower = ((lane & j) == 0);
                bool up    = ((lane & k) == 0);
                unsigned int mn = v < pv ? v : pv;
                unsigned int mx = v < pv ? pv : v;
                v = (lower == up) ? mn : mx;
            }
        }
        if (lane == 26) tpv[wid][r] = v;   // 38th largest lane-max
        if (lane == 63) rmx[wid][r] = v;   // row max
    }
    unsigned int Tpiv[8];
#pragma unroll
    for (int r = 0; r < 8; ++r) Tpiv[r] = tpv[wid][r];

    // ---- PASS 2: recompute dots, push candidates >= pivot --------------
#pragma unroll
    for (int i = 0; i < 2; ++i) {
        int r  = wid * 2 + i;
        int kk = r >> 2, cc = r & 3;
        gload_lds16(Kb + ((size_t)(2 * p + kk)) * 32 + h * 16 + cc * 4, &Kl[0][r * 256]);
    }
    asm volatile("s_waitcnt vmcnt(0)" ::: "memory");
    __syncthreads();

    for (int t = 0; t < 32; ++t) {
        const int buf = t & 1;
        if (t < 31) {
#pragma unroll
            for (int i = 0; i < 2; ++i) {
                int r  = wid * 2 + i;
                int kk = r >> 2, cc = r & 3;
                gload_lds16(Kb + ((size_t)((t + 1) * 64 + 2 * p + kk)) * 32 + h * 16 + cc * 4,
                            &Kl[buf ^ 1][r * 256]);
            }
        }
        float a[8], e[8];
#pragma unroll
        for (int r = 0; r < 8; ++r) { a[r] = 0.f; e[r] = 0.f; }
#pragma unroll
        for (int c = 0; c < 4; ++c) {
            float4 kva = *(const float4*)&Kl[buf][c * 256 + lane * 4];
            float4 kvb = *(const float4*)&Kl[buf][(4 + c) * 256 + lane * 4];
#pragma unroll
            for (int r = 0; r < 8; ++r) {
                a[r] += q[r][c*4+0]*kva.x + q[r][c*4+1]*kva.y + q[r][c*4+2]*kva.z + q[r][c*4+3]*kva.w;
                e[r] += q[r][c*4+0]*kvb.x + q[r][c*4+1]*kvb.y + q[r][c*4+2]*kvb.z + q[r][c*4+3]*kvb.w;
            }
        }
        const int kidx = t * 64 + 2 * p + h;
#pragma unroll
        for (int r = 0; r < 8; ++r) {
            float fa = a[r] + __shfl_xor(a[r], 32);
            float fe = e[r] + __shfl_xor(e[r], 32);
            unsigned int k = sortkey(h ? fe : fa);
            if (k >= Tpiv[r]) {
                int slot = atomicAdd(&lcnt[wid][r], 1);
                if (slot < CAP) { lvk[wid][r][slot] = k; lix[wid][r][slot] = kidx; }
            }
        }
        asm volatile("s_waitcnt vmcnt(0)" ::: "memory");
        __syncthreads();
    }

    // ---- per-row: exact radix select over candidates, softmax, PV ------
    for (int r = 0; r < 8; ++r) {
        int cnt = lcnt[wid][r]; if (cnt > CAP) cnt = CAP;
        const float rmaxf = key2f(rmx[wid][r]);

        unsigned int prefix = 0;
        int need = UTOP;
#pragma unroll
        for (int pass = 0; pass < 4; ++pass) {
            const int sh = 24 - pass * 8;
            *(int4*)&hist[wid][lane * 4] = make_int4(0, 0, 0, 0);
            for (int i = lane; i < cnt; i += 64) {
                unsigned int key = lvk[wid][r][i];
                bool msk = (pass == 0) || ((key >> (sh + 8)) == (prefix >> (sh + 8)));
                if (msk) atomicAdd(&hist[wid][(key >> sh) & 255], 1);
            }
            int4 hb = *(const int4*)&hist[wid][lane * 4];
            int csum = hb.x + hb.y + hb.z + hb.w;
            int suf = csum;
#pragma unroll
            for (int off = 1; off < 64; off <<= 1) {
                int o = __shfl_down(suf, off);
                if (lane + off < 64) suf += o;
            }
            int above = suf - csum;
            bool found = (above < need) && (above + csum >= need);
            unsigned int cp = 0; int cn = 0;
            if (found) {
                int cum = above, dd, na;
                if (cum + hb.w >= need)      { dd = 3; na = cum; }
                else { cum += hb.w;
                if (cum + hb.z >= need)      { dd = 2; na = cum; }
                else { cum += hb.z;
                if (cum + hb.y >= need)      { dd = 1; na = cum; }
                else { cum += hb.y;            dd = 0; na = cum; } } }
                cp = prefix | ((unsigned int)(lane * 4 + dd) << sh);
                cn = need - na;
            }
            unsigned long long bal = __ballot(found);
            int wl = (int)(__ffsll(bal) - 1);
            prefix = (unsigned int)__shfl((int)cp, wl);
            need   = __shfl(cn, wl);
        }
        const unsigned int thrkey = prefix;   // exact 38th-largest key

        float psum = 0.f;
        for (int i = lane; i < cnt; i += 64) {
            unsigned int key = lvk[wid][r][i];
            if (key >= thrkey) psum += expf(key2f(key) - rmaxf);
        }
#pragma unroll
        for (int off = 32; off >= 1; off >>= 1) psum += __shfl_xor(psum, off);
        float inv = 1.0f / psum;

        float acc = 0.f;
        for (int i = h; i < cnt; i += 2) {
            unsigned int key = lvk[wid][r][i];
            float w = (key >= thrkey) ? expf(key2f(key) - rmaxf) : 0.f;
            acc += w * Vb[(size_t)lix[wid][r][i] * D_K + p];
        }
        acc += __shfl_xor(acc, 32);
        if (lane < 32)
            ctxb[((size_t)(b * LSEQ) + row0 + r) * D_MODEL + hh * D_K + p] = acc * inv;
    }
}

// ---------------------------------------------------------------------------
// Residual add + LayerNorm over 256, in place into h. One wave per row.
// ---------------------------------------------------------------------------
__global__ __launch_bounds__(64) void k_addln(float* __restrict__ h,
                                              const float* __restrict__ a,
                                              const float* __restrict__ g,
                                              const float* __restrict__ bb) {
    int row = blockIdx.x, lane = threadIdx.x;
    float4 hv = *(const float4*)&h[(size_t)row * D_MODEL + lane * 4];
    float4 av = *(const float4*)&a[(size_t)row * D_MODEL + lane * 4];
    float x0 = hv.x + av.x, x1 = hv.y + av.y, x2 = hv.z + av.z, x3 = hv.w + av.w;
    float s = x0 + x1 + x2 + x3;
#pragma unroll
    for (int off = 32; off >= 1; off >>= 1) s += __shfl_xor(s, off);
    float mean = s * (1.0f / 256.0f);
    float d0 = x0 - mean, d1 = x1 - mean, d2 = x2 - mean, d3 = x3 - mean;
    float vs = d0 * d0 + d1 * d1 + d2 * d2 + d3 * d3;
#pragma unroll
    for (int off = 32; off >= 1; off >>= 1) vs += __shfl_xor(vs, off);
    float inv = rsqrtf(vs * (1.0f / 256.0f) + 1e-5f);
    float4 gv = *(const float4*)&g[lane * 4];
    float4 bv = *(const float4*)&bb[lane * 4];
    float4 o;
    o.x = d0 * inv * gv.x + bv.x;
    o.y = d1 * inv * gv.y + bv.y;
    o.z = d2 * inv * gv.z + bv.z;
    o.w = d3 * inv * gv.w + bv.w;
    *(float4*)&h[(size_t)row * D_MODEL + lane * 4] = o;
}

// ---------------------------------------------------------------------------
// Decoder head
// ---------------------------------------------------------------------------
__global__ __launch_bounds__(64) void k_dec(const float* __restrict__ h,
                                            const float* __restrict__ w,
                                            const float* __restrict__ b,
                                            float* __restrict__ out) {
    int row = blockIdx.x, lane = threadIdx.x;
    int c = lane & 7, part = lane >> 3;   // 8 parts x 32 dims
    float acc = 0.f;
    int d0 = part * 32;
#pragma unroll
    for (int dd = 0; dd < 32; ++dd) acc += h[(size_t)row * D_MODEL + d0 + dd] * w[(d0 + dd) * 8 + c];
    acc += __shfl_xor(acc, 8);
    acc += __shfl_xor(acc, 16);
    acc += __shfl_xor(acc, 32);
    if (lane < 8) out[(size_t)row * 8 + c] = acc + b[c];
}

// ---------------------------------------------------------------------------
extern "C" void kernel_launch(void* const* d_in, const int* in_sizes, int n_in,
                              void* d_out, int out_size, void* d_ws, size_t ws_size,
                              hipStream_t stream) {
    const float* x     = (const float*)d_in[0];
    const float* emb_w = (const float*)d_in[1];
    const float* emb_b = (const float*)d_in[2];
    const float* wq    = (const float*)d_in[3];
    const float* bq    = (const float*)d_in[4];
    const float* wk    = (const float*)d_in[5];
    const float* bk    = (const float*)d_in[6];
    const float* wv    = (const float*)d_in[7];
    const float* bv    = (const float*)d_in[8];
    const float* wo    = (const float*)d_in[9];
    const float* bo    = (const float*)d_in[10];
    const float* ln1_g = (const float*)d_in[11];
    const float* ln1_b = (const float*)d_in[12];
    const float* ln2_g = (const float*)d_in[13];
    const float* ln2_b = (const float*)d_in[14];
    const float* ff1_w = (const float*)d_in[15];
    const float* ff1_b = (const float*)d_in[16];
    const float* ff2_w = (const float*)d_in[17];
    const float* ff2_b = (const float*)d_in[18];
    const float* dec_w = (const float*)d_in[19];
    const float* dec_b = (const float*)d_in[20];

    float* ws   = (float*)d_ws;
    float* h    = ws;                      // 4096*256   = 1M floats
    float* qb   = h    + (1 << 20);
    float* kb   = qb   + (1 << 20);
    float* vb   = kb   + (1 << 20);
    float* ctxb = vb   + (1 << 20);
    float* tmp  = ctxb + (1 << 20);
    float* ffb  = tmp  + (1 << 20);        // 4096*1024 = 4M

    k_embed<<<ROWS, 256, 0, stream>>>(x, emb_w, emb_b, h);

    for (int l = 0; l < 2; ++l) {
        const float* wql = wq + (size_t)l * 65536;  const float* bql = bq + l * 256;
        const float* wkl = wk + (size_t)l * 65536;  const float* bkl = bk + l * 256;
        const float* wvl = wv + (size_t)l * 65536;  const float* bvl = bv + l * 256;
        const float* wol = wo + (size_t)l * 65536;  const float* bol = bo + l * 256;

        dim3 g4(64, 4);
        k_gemm<2><<<g4, 256, 0, stream>>>(h, wql, bql, qb, ROWS, 256, 256);
        k_gemm<2><<<g4, 256, 0, stream>>>(h, wkl, bkl, kb, ROWS, 256, 256);
        k_gemm<2><<<g4, 256, 0, stream>>>(h, wvl, bvl, vb, ROWS, 256, 256);

        k_attn<<<NHEAD * BATCH * 64, 256, 0, stream>>>(qb, kb, vb, ctxb);

        k_gemm<0><<<g4, 256, 0, stream>>>(ctxb, wol, bol, tmp, ROWS, 256, 256);
        k_addln<<<ROWS, 64, 0, stream>>>(h, tmp, ln1_g + l * 256, ln1_b + l * 256);

        dim3 g16(64, 16);
        k_gemm<1><<<g16, 256, 0, stream>>>(h, ff1_w + (size_t)l * 262144, ff1_b + l * 1024,
                                           ffb, ROWS, D_FF, 256);
        k_gemm<0><<<g4, 256, 0, stream>>>(ffb, ff2_w + (size_t)l * 262144, ff2_b + l * 256,
                                          tmp, ROWS, 256, D_FF);
        k_addln<<<ROWS, 64, 0, stream>>>(h, tmp, ln2_g + l * 256, ln2_b + l * 256);
    }

    k_dec<<<ROWS, 64, 0, stream>>>(h, dec_w, dec_b, (float*)d_out);
}

// Round 8
// 1073.648 us; speedup vs baseline: 3.7794x; 1.1098x over previous
//
#include <hip/hip_runtime.h>
#include <math.h>

#define D_MODEL 256
#define NHEAD   8
#define D_K     32
#define LSEQ    2048
#define BATCH   2
#define ROWS    (BATCH * LSEQ)   // 4096
#define D_FF    1024
#define UTOP    38
#define CAP     240

// ---------------------------------------------------------------------------
// Embedding + positional encoding
// ---------------------------------------------------------------------------
__global__ __launch_bounds__(256) void k_embed(const float* __restrict__ x,
                                               const float* __restrict__ w,
                                               const float* __restrict__ b,
                                               float* __restrict__ h) {
    int row = blockIdx.x;           // b*L + l
    int l   = row & (LSEQ - 1);
    int d   = threadIdx.x;
    __shared__ float xs[32];
    if (d < 32) xs[d] = x[row * 32 + d];
    __syncthreads();
    float acc = 0.f;
#pragma unroll
    for (int i = 0; i < 32; ++i) acc += xs[i] * w[i * D_MODEL + d];
    acc = (acc + b[d]) * 16.0f;     // sqrt(256)
    int m = d >> 1;
    float div = expf(-(float)(2 * m) * (9.210340371976184f / 256.0f)); // ln(1e4)/256
    float ang = (float)l * div;
    float pe = (d & 1) ? cosf(ang) : sinf(ang);
    h[row * D_MODEL + d] = acc + pe;
}

// ---------------------------------------------------------------------------
// Generic fp32 tiled GEMM: C = A[M,K] @ W[K,N] + bias
// MODE 0: plain   MODE 1: relu   MODE 2: scatter to q/k/v layout [B,H,L,32]
// ---------------------------------------------------------------------------
template <int MODE>
__global__ __launch_bounds__(256) void k_gemm(const float* __restrict__ A,
                                              const float* __restrict__ W,
                                              const float* __restrict__ bias,
                                              float* __restrict__ C,
                                              int M, int N, int K) {
    __shared__ float As[16][68];
    __shared__ float Ws[16][68];
    const int t  = threadIdx.x;
    const int tx = t & 15, ty = t >> 4;
    const int m0 = blockIdx.x * 64, n0 = blockIdx.y * 64;
    float acc[4][4] = {};
    for (int k0 = 0; k0 < K; k0 += 16) {
        {
            int mr = t >> 2, kc = (t & 3) * 4;
            float4 av = *(const float4*)&A[(size_t)(m0 + mr) * K + k0 + kc];
            As[kc + 0][mr] = av.x; As[kc + 1][mr] = av.y;
            As[kc + 2][mr] = av.z; As[kc + 3][mr] = av.w;
            int kr = t >> 4, nc = (t & 15) * 4;
            *(float4*)&Ws[kr][nc] = *(const float4*)&W[(size_t)(k0 + kr) * N + n0 + nc];
        }
        __syncthreads();
#pragma unroll
        for (int k = 0; k < 16; ++k) {
            float4 a4 = *(const float4*)&As[k][ty * 4];
            float4 w4 = *(const float4*)&Ws[k][tx * 4];
            float av[4] = {a4.x, a4.y, a4.z, a4.w};
            float wv[4] = {w4.x, w4.y, w4.z, w4.w};
#pragma unroll
            for (int i = 0; i < 4; ++i)
#pragma unroll
                for (int j = 0; j < 4; ++j) acc[i][j] += av[i] * wv[j];
        }
        __syncthreads();
    }
#pragma unroll
    for (int i = 0; i < 4; ++i) {
        int row = m0 + ty * 4 + i;
#pragma unroll
        for (int j = 0; j < 4; ++j) {
            int col = n0 + tx * 4 + j;
            float v = acc[i][j] + bias[col];
            if (MODE == 1) v = fmaxf(v, 0.f);
            if (MODE == 2) {
                int bb = row >> 11, ll = row & (LSEQ - 1);
                int hh = col >> 5, dd = col & 31;
                C[(((size_t)(bb * NHEAD + hh) * LSEQ) + ll) * D_K + dd] = v;
            } else {
                C[(size_t)row * N + col] = v;
            }
        }
    }
}

// ---------------------------------------------------------------------------
// Fused ProbSparse attention, v7 — pivot select, 4 rows/wave, 3 blocks/CU.
// Same algorithm as v6 (verified): two QK passes over LDS-staged K tiles,
// pivot = 38th-largest of 64 lane-maxes (bitonic), candidate push >= pivot,
// exact radix-select threshold over the small list, softmax + PV gather.
// Changes: rows/wave 8->4 (q = 64 VGPR, no AGPR shuttle), CAP 240 with
// 16 rows/block => LDS ~52 KB => 3 blocks/CU, pivot broadcast via shfl,
// XCD-aware block swizzle for K-panel L2/HBM locality.
// ---------------------------------------------------------------------------
__device__ __forceinline__ unsigned int sortkey(float f) {
    unsigned int u = __float_as_uint(f);
    return (u & 0x80000000u) ? ~u : (u | 0x80000000u);
}
__device__ __forceinline__ float key2f(unsigned int u) {
    unsigned int b = (u & 0x80000000u) ? (u ^ 0x80000000u) : ~u;
    return __uint_as_float(b);
}
__device__ __forceinline__ void gload_lds16(const float* src, float* ldsDst) {
    __builtin_amdgcn_global_load_lds(
        (const __attribute__((address_space(1))) unsigned int*)src,
        (__attribute__((address_space(3))) unsigned int*)ldsDst,
        16, 0, 0);
}

__global__ __launch_bounds__(256, 3) void k_attn(const float* __restrict__ Q,
                                                 const float* __restrict__ Kt,
                                                 const float* __restrict__ Vt,
                                                 float* __restrict__ ctxb) {
    __shared__ float        Kl[2][2048];        // 16 KB   K tile double-buffer
    __shared__ unsigned int lvk[4][4][CAP];     // 15 KB   candidate keys
    __shared__ int          lix[4][4][CAP];     // 15 KB   candidate indices
    __shared__ int          hist[4][256];       // 4 KB    radix histogram
    __shared__ int          lcnt[4][4];

    const int tid   = threadIdx.x;
    const int lane  = tid & 63;
    const int wid   = tid >> 6;
    // XCD-aware swizzle: grid 2048 = 8 XCDs x 256; consecutive logical ids
    // (same bh) land on one XCD.
    const int lbid  = (blockIdx.x & 7) * 256 + (blockIdx.x >> 3);
    const int bh    = lbid >> 7;                // 16 bh x 128 chunks
    const int chunk = lbid & 127;
    const int row0  = chunk * 16 + wid * 4;     // 4 rows per wave
    const int b     = bh >> 3, hh = bh & 7;
    const int h     = lane >> 5;                // d-half owned by this lane
    const int p     = lane & 31;

    const float* Kb = Kt + (size_t)bh * LSEQ * D_K;
    const float* Vb = Vt + (size_t)bh * LSEQ * D_K;
    const float* qp = Q + ((size_t)bh * LSEQ + row0) * D_K;

    const float scale = 0.17677669529663687f;   // 1/sqrt(32)
    float q[4][16];
#pragma unroll
    for (int r = 0; r < 4; ++r)
#pragma unroll
        for (int i = 0; i < 16; ++i)
            q[r][i] = qp[r * 32 + h * 16 + i] * scale;

    // ---- PASS 1: dots, track lane-max per row --------------------------
    unsigned int lmax[4];
#pragma unroll
    for (int r = 0; r < 4; ++r) lmax[r] = 0u;

#pragma unroll
    for (int i = 0; i < 2; ++i) {
        int r  = wid * 2 + i;
        int kk = r >> 2, cc = r & 3;
        gload_lds16(Kb + ((size_t)(2 * p + kk)) * 32 + h * 16 + cc * 4, &Kl[0][r * 256]);
    }
    asm volatile("s_waitcnt vmcnt(0)" ::: "memory");
    __syncthreads();

    for (int t = 0; t < 32; ++t) {
        const int buf = t & 1;
        if (t < 31) {
#pragma unroll
            for (int i = 0; i < 2; ++i) {
                int r  = wid * 2 + i;
                int kk = r >> 2, cc = r & 3;
                gload_lds16(Kb + ((size_t)((t + 1) * 64 + 2 * p + kk)) * 32 + h * 16 + cc * 4,
                            &Kl[buf ^ 1][r * 256]);
            }
        }
        float a[4], e[4];
#pragma unroll
        for (int r = 0; r < 4; ++r) { a[r] = 0.f; e[r] = 0.f; }
#pragma unroll
        for (int c = 0; c < 4; ++c) {
            float4 kva = *(const float4*)&Kl[buf][c * 256 + lane * 4];        // key 2p
            float4 kvb = *(const float4*)&Kl[buf][(4 + c) * 256 + lane * 4];  // key 2p+1
#pragma unroll
            for (int r = 0; r < 4; ++r) {
                a[r] += q[r][c*4+0]*kva.x + q[r][c*4+1]*kva.y + q[r][c*4+2]*kva.z + q[r][c*4+3]*kva.w;
                e[r] += q[r][c*4+0]*kvb.x + q[r][c*4+1]*kvb.y + q[r][c*4+2]*kvb.z + q[r][c*4+3]*kvb.w;
            }
        }
#pragma unroll
        for (int r = 0; r < 4; ++r) {
            float fa = a[r] + __shfl_xor(a[r], 32);
            float fe = e[r] + __shfl_xor(e[r], 32);
            unsigned int k = sortkey(h ? fe : fa);   // lane owns key 2p+h
            if (k > lmax[r]) lmax[r] = k;
        }
        asm volatile("s_waitcnt vmcnt(0)" ::: "memory");
        __syncthreads();
    }

    // ---- pivot per row: bitonic-sort 64 lane-maxes, broadcast via shfl --
    unsigned int Tpiv[4];
    float        rmaxf[4];
#pragma unroll
    for (int r = 0; r < 4; ++r) {
        unsigned int v = lmax[r];
#pragma unroll
        for (int k = 2; k <= 64; k <<= 1) {
#pragma unroll
            for (int j = k >> 1; j >= 1; j >>= 1) {
                unsigned int pv = (unsigned int)__shfl_xor((int)v, j);
                bool lower = ((lane & j) == 0);
                bool up    = ((lane & k) == 0);
                unsigned int mn = v < pv ? v : pv;
                unsigned int mx = v < pv ? pv : v;
                v = (lower == up) ? mn : mx;
            }
        }
        Tpiv[r]  = (unsigned int)__shfl((int)v, 26);  // 38th-largest lane-max
        rmaxf[r] = key2f((unsigned int)__shfl((int)v, 63));
    }
    if (lane < 4) lcnt[wid][lane] = 0;

    // ---- PASS 2: recompute dots, push candidates >= pivot --------------
#pragma unroll
    for (int i = 0; i < 2; ++i) {
        int r  = wid * 2 + i;
        int kk = r >> 2, cc = r & 3;
        gload_lds16(Kb + ((size_t)(2 * p + kk)) * 32 + h * 16 + cc * 4, &Kl[0][r * 256]);
    }
    asm volatile("s_waitcnt vmcnt(0)" ::: "memory");
    __syncthreads();

    for (int t = 0; t < 32; ++t) {
        const int buf = t & 1;
        if (t < 31) {
#pragma unroll
            for (int i = 0; i < 2; ++i) {
                int r  = wid * 2 + i;
                int kk = r >> 2, cc = r & 3;
                gload_lds16(Kb + ((size_t)((t + 1) * 64 + 2 * p + kk)) * 32 + h * 16 + cc * 4,
                            &Kl[buf ^ 1][r * 256]);
            }
        }
        float a[4], e[4];
#pragma unroll
        for (int r = 0; r < 4; ++r) { a[r] = 0.f; e[r] = 0.f; }
#pragma unroll
        for (int c = 0; c < 4; ++c) {
            float4 kva = *(const float4*)&Kl[buf][c * 256 + lane * 4];
            float4 kvb = *(const float4*)&Kl[buf][(4 + c) * 256 + lane * 4];
#pragma unroll
            for (int r = 0; r < 4; ++r) {
                a[r] += q[r][c*4+0]*kva.x + q[r][c*4+1]*kva.y + q[r][c*4+2]*kva.z + q[r][c*4+3]*kva.w;
                e[r] += q[r][c*4+0]*kvb.x + q[r][c*4+1]*kvb.y + q[r][c*4+2]*kvb.z + q[r][c*4+3]*kvb.w;
            }
        }
        const int kidx = t * 64 + 2 * p + h;
#pragma unroll
        for (int r = 0; r < 4; ++r) {
            float fa = a[r] + __shfl_xor(a[r], 32);
            float fe = e[r] + __shfl_xor(e[r], 32);
            unsigned int k = sortkey(h ? fe : fa);
            if (k >= Tpiv[r]) {
                int slot = atomicAdd(&lcnt[wid][r], 1);
                if (slot < CAP) { lvk[wid][r][slot] = k; lix[wid][r][slot] = kidx; }
            }
        }
        asm volatile("s_waitcnt vmcnt(0)" ::: "memory");
        __syncthreads();
    }

    // ---- per-row: exact radix select over candidates, softmax, PV ------
    for (int r = 0; r < 4; ++r) {
        int cnt = lcnt[wid][r]; if (cnt > CAP) cnt = CAP;

        unsigned int prefix = 0;
        int need = UTOP;
#pragma unroll
        for (int pass = 0; pass < 4; ++pass) {
            const int sh = 24 - pass * 8;
            *(int4*)&hist[wid][lane * 4] = make_int4(0, 0, 0, 0);
            for (int i = lane; i < cnt; i += 64) {
                unsigned int key = lvk[wid][r][i];
                bool msk = (pass == 0) || ((key >> (sh + 8)) == (prefix >> (sh + 8)));
                if (msk) atomicAdd(&hist[wid][(key >> sh) & 255], 1);
            }
            int4 hb = *(const int4*)&hist[wid][lane * 4];
            int csum = hb.x + hb.y + hb.z + hb.w;
            int suf = csum;
#pragma unroll
            for (int off = 1; off < 64; off <<= 1) {
                int o = __shfl_down(suf, off);
                if (lane + off < 64) suf += o;
            }
            int above = suf - csum;
            bool found = (above < need) && (above + csum >= need);
            unsigned int cp = 0; int cn = 0;
            if (found) {
                int cum = above, dd, na;
                if (cum + hb.w >= need)      { dd = 3; na = cum; }
                else { cum += hb.w;
                if (cum + hb.z >= need)      { dd = 2; na = cum; }
                else { cum += hb.z;
                if (cum + hb.y >= need)      { dd = 1; na = cum; }
                else { cum += hb.y;            dd = 0; na = cum; } } }
                cp = prefix | ((unsigned int)(lane * 4 + dd) << sh);
                cn = need - na;
            }
            unsigned long long bal = __ballot(found);
            int wl = (int)(__ffsll(bal) - 1);
            prefix = (unsigned int)__shfl((int)cp, wl);
            need   = __shfl(cn, wl);
        }
        const unsigned int thrkey = prefix;   // exact 38th-largest key

        float psum = 0.f;
        for (int i = lane; i < cnt; i += 64) {
            unsigned int key = lvk[wid][r][i];
            if (key >= thrkey) psum += expf(key2f(key) - rmaxf[r]);
        }
#pragma unroll
        for (int off = 32; off >= 1; off >>= 1) psum += __shfl_xor(psum, off);
        float inv = 1.0f / psum;

        float acc = 0.f;
        for (int i = h; i < cnt; i += 2) {
            unsigned int key = lvk[wid][r][i];
            float w = (key >= thrkey) ? expf(key2f(key) - rmaxf[r]) : 0.f;
            acc += w * Vb[(size_t)lix[wid][r][i] * D_K + p];
        }
        acc += __shfl_xor(acc, 32);
        if (lane < 32)
            ctxb[((size_t)(b * LSEQ) + row0 + r) * D_MODEL + hh * D_K + p] = acc * inv;
    }
}

// ---------------------------------------------------------------------------
// Residual add + LayerNorm over 256, in place into h. One wave per row.
// ---------------------------------------------------------------------------
__global__ __launch_bounds__(64) void k_addln(float* __restrict__ h,
                                              const float* __restrict__ a,
                                              const float* __restrict__ g,
                                              const float* __restrict__ bb) {
    int row = blockIdx.x, lane = threadIdx.x;
    float4 hv = *(const float4*)&h[(size_t)row * D_MODEL + lane * 4];
    float4 av = *(const float4*)&a[(size_t)row * D_MODEL + lane * 4];
    float x0 = hv.x + av.x, x1 = hv.y + av.y, x2 = hv.z + av.z, x3 = hv.w + av.w;
    float s = x0 + x1 + x2 + x3;
#pragma unroll
    for (int off = 32; off >= 1; off >>= 1) s += __shfl_xor(s, off);
    float mean = s * (1.0f / 256.0f);
    float d0 = x0 - mean, d1 = x1 - mean, d2 = x2 - mean, d3 = x3 - mean;
    float vs = d0 * d0 + d1 * d1 + d2 * d2 + d3 * d3;
#pragma unroll
    for (int off = 32; off >= 1; off >>= 1) vs += __shfl_xor(vs, off);
    float inv = rsqrtf(vs * (1.0f / 256.0f) + 1e-5f);
    float4 gv = *(const float4*)&g[lane * 4];
    float4 bv = *(const float4*)&bb[lane * 4];
    float4 o;
    o.x = d0 * inv * gv.x + bv.x;
    o.y = d1 * inv * gv.y + bv.y;
    o.z = d2 * inv * gv.z + bv.z;
    o.w = d3 * inv * gv.w + bv.w;
    *(float4*)&h[(size_t)row * D_MODEL + lane * 4] = o;
}

// ---------------------------------------------------------------------------
// Decoder head
// ---------------------------------------------------------------------------
__global__ __launch_bounds__(64) void k_dec(const float* __restrict__ h,
                                            const float* __restrict__ w,
                                            const float* __restrict__ b,
                                            float* __restrict__ out) {
    int row = blockIdx.x, lane = threadIdx.x;
    int c = lane & 7, part = lane >> 3;   // 8 parts x 32 dims
    float acc = 0.f;
    int d0 = part * 32;
#pragma unroll
    for (int dd = 0; dd < 32; ++dd) acc += h[(size_t)row * D_MODEL + d0 + dd] * w[(d0 + dd) * 8 + c];
    acc += __shfl_xor(acc, 8);
    acc += __shfl_xor(acc, 16);
    acc += __shfl_xor(acc, 32);
    if (lane < 8) out[(size_t)row * 8 + c] = acc + b[c];
}

// ---------------------------------------------------------------------------
extern "C" void kernel_launch(void* const* d_in, const int* in_sizes, int n_in,
                              void* d_out, int out_size, void* d_ws, size_t ws_size,
                              hipStream_t stream) {
    const float* x     = (const float*)d_in[0];
    const float* emb_w = (const float*)d_in[1];
    const float* emb_b = (const float*)d_in[2];
    const float* wq    = (const float*)d_in[3];
    const float* bq    = (const float*)d_in[4];
    const float* wk    = (const float*)d_in[5];
    const float* bk    = (const float*)d_in[6];
    const float* wv    = (const float*)d_in[7];
    const float* bv    = (const float*)d_in[8];
    const float* wo    = (const float*)d_in[9];
    const float* bo    = (const float*)d_in[10];
    const float* ln1_g = (const float*)d_in[11];
    const float* ln1_b = (const float*)d_in[12];
    const float* ln2_g = (const float*)d_in[13];
    const float* ln2_b = (const float*)d_in[14];
    const float* ff1_w = (const float*)d_in[15];
    const float* ff1_b = (const float*)d_in[16];
    const float* ff2_w = (const float*)d_in[17];
    const float* ff2_b = (const float*)d_in[18];
    const float* dec_w = (const float*)d_in[19];
    const float* dec_b = (const float*)d_in[20];

    float* ws   = (float*)d_ws;
    float* h    = ws;                      // 4096*256   = 1M floats
    float* qb   = h    + (1 << 20);
    float* kb   = qb   + (1 << 20);
    float* vb   = kb   + (1 << 20);
    float* ctxb = vb   + (1 << 20);
    float* tmp  = ctxb + (1 << 20);
    float* ffb  = tmp  + (1 << 20);        // 4096*1024 = 4M

    k_embed<<<ROWS, 256, 0, stream>>>(x, emb_w, emb_b, h);

    for (int l = 0; l < 2; ++l) {
        const float* wql = wq + (size_t)l * 65536;  const float* bql = bq + l * 256;
        const float* wkl = wk + (size_t)l * 65536;  const float* bkl = bk + l * 256;
        const float* wvl = wv + (size_t)l * 65536;  const float* bvl = bv + l * 256;
        const float* wol = wo + (size_t)l * 65536;  const float* bol = bo + l * 256;

        dim3 g4(64, 4);
        k_gemm<2><<<g4, 256, 0, stream>>>(h, wql, bql, qb, ROWS, 256, 256);
        k_gemm<2><<<g4, 256, 0, stream>>>(h, wkl, bkl, kb, ROWS, 256, 256);
        k_gemm<2><<<g4, 256, 0, stream>>>(h, wvl, bvl, vb, ROWS, 256, 256);

        k_attn<<<NHEAD * BATCH * 128, 256, 0, stream>>>(qb, kb, vb, ctxb);

        k_gemm<0><<<g4, 256, 0, stream>>>(ctxb, wol, bol, tmp, ROWS, 256, 256);
        k_addln<<<ROWS, 64, 0, stream>>>(h, tmp, ln1_g + l * 256, ln1_b + l * 256);

        dim3 g16(64, 16);
        k_gemm<1><<<g16, 256, 0, stream>>>(h, ff1_w + (size_t)l * 262144, ff1_b + l * 1024,
                                           ffb, ROWS, D_FF, 256);
        k_gemm<0><<<g4, 256, 0, stream>>>(ffb, ff2_w + (size_t)l * 262144, ff2_b + l * 256,
                                          tmp, ROWS, 256, D_FF);
        k_addln<<<ROWS, 64, 0, stream>>>(h, tmp, ln2_g + l * 256, ln2_b + l * 256);
    }

    k_dec<<<ROWS, 64, 0, stream>>>(h, dec_w, dec_b, (float*)d_out);
}